// Round 1
// baseline (647.287 us; speedup 1.0000x reference)
//
#include <hip/hip_runtime.h>
#include <hip/hip_bf16.h>

// ---------------------------------------------------------------------------
// GCN encoder: h1 = relu(P (x W1) + b1); mu = P (h1 Wmu) + bmu; ls likewise.
// P = D^-1/2 (A + I) D^-1/2 with in-degree-based D (cols are targets).
// Strategy: build CSR (edges grouped by target) so propagation is a
// gather-reduce (no atomics on the feature vectors); use P(XW) = (PX)W to
// share ONE propagation between mu and logstd.
// ---------------------------------------------------------------------------

__global__ void k_zero_int(int* __restrict__ p, int n) {
    int i = blockIdx.x * blockDim.x + threadIdx.x;
    if (i < n) p[i] = 0;
}

__global__ void k_count(const int* __restrict__ col, int e, int* __restrict__ cnt) {
    int i = blockIdx.x * blockDim.x + threadIdx.x;
    if (i < e) atomicAdd(&cnt[col[i]], 1);
}

__global__ void k_dinv(const int* __restrict__ cnt, float* __restrict__ dinv, int n) {
    int i = blockIdx.x * blockDim.x + threadIdx.x;
    if (i < n) dinv[i] = 1.0f / sqrtf((float)(cnt[i] + 1));   // +1 self loop; always > 0
}

// ---- hierarchical exclusive scan of cnt[] -> offs[] (chunk = 1024) ----
__global__ void k_bsum(const int* __restrict__ cnt, int n, int* __restrict__ bsum) {
    __shared__ int sh[256];
    int b = blockIdx.x, tid = threadIdx.x;
    int i0 = b * 1024 + tid * 4;
    int s = 0;
    if (i0 + 3 < n) {
        s = cnt[i0] + cnt[i0 + 1] + cnt[i0 + 2] + cnt[i0 + 3];
    } else {
        for (int c = 0; c < 4; ++c) if (i0 + c < n) s += cnt[i0 + c];
    }
    sh[tid] = s; __syncthreads();
    for (int d = 128; d > 0; d >>= 1) {
        if (tid < d) sh[tid] += sh[tid + d];
        __syncthreads();
    }
    if (tid == 0) bsum[b] = sh[0];
}

__global__ void k_scan_bsum(const int* __restrict__ bsum, int nb, int* __restrict__ bbase) {
    __shared__ int sh[128];
    int t = threadIdx.x;
    int v = (t < nb) ? bsum[t] : 0;
    sh[t] = v; __syncthreads();
    for (int d = 1; d < 128; d <<= 1) {
        int u = (t >= d) ? sh[t - d] : 0;
        __syncthreads();
        sh[t] += u;
        __syncthreads();
    }
    if (t < nb) bbase[t] = sh[t] - v;   // exclusive
}

__global__ void k_scan_local(const int* __restrict__ cnt, const int* __restrict__ bbase,
                             int* __restrict__ offs, int* __restrict__ cursor, int n) {
    __shared__ int sh[256];
    int b = blockIdx.x, tid = threadIdx.x;
    int i0 = b * 1024 + tid * 4;
    int v0 = (i0 + 0 < n) ? cnt[i0 + 0] : 0;
    int v1 = (i0 + 1 < n) ? cnt[i0 + 1] : 0;
    int v2 = (i0 + 2 < n) ? cnt[i0 + 2] : 0;
    int v3 = (i0 + 3 < n) ? cnt[i0 + 3] : 0;
    int ts = v0 + v1 + v2 + v3;
    sh[tid] = ts; __syncthreads();
    for (int d = 1; d < 256; d <<= 1) {
        int t = (tid >= d) ? sh[tid - d] : 0;
        __syncthreads();
        sh[tid] += t;
        __syncthreads();
    }
    int excl = sh[tid] - ts + bbase[b];
    int o0 = excl, o1 = o0 + v0, o2 = o1 + v1, o3 = o2 + v2;
    if (i0 + 0 < n) { offs[i0 + 0] = o0; cursor[i0 + 0] = o0; }
    if (i0 + 1 < n) { offs[i0 + 1] = o1; cursor[i0 + 1] = o1; }
    if (i0 + 2 < n) { offs[i0 + 2] = o2; cursor[i0 + 2] = o2; }
    if (i0 + 3 < n) { offs[i0 + 3] = o3; cursor[i0 + 3] = o3; }
}

__global__ void k_fill(const int* __restrict__ row, const int* __restrict__ col, int e,
                       int* __restrict__ cursor, int* __restrict__ esrc) {
    int i = blockIdx.x * blockDim.x + threadIdx.x;
    if (i < e) {
        int c = col[i];
        int p = atomicAdd(&cursor[c], 1);
        esrc[p] = row[i];
    }
}

// ---- propagation: one wave per node, 2 feats/lane (128 feats) ----
// out[v] = dinv[v] * ( sum_{e: col=v} dinv[src]*h[src] + dinv[v]*h[v] ) (+bias)(relu)
__global__ __launch_bounds__(256) void k_prop(
    const float* __restrict__ h, const float* __restrict__ dinv,
    const int* __restrict__ offs, const int* __restrict__ cnt,
    const int* __restrict__ esrc, float* __restrict__ out,
    const float* __restrict__ bias, int do_relu, int n)
{
    int wid  = (blockIdx.x * blockDim.x + threadIdx.x) >> 6;
    int lane = threadIdx.x & 63;
    if (wid >= n) return;
    int v = wid;
    float dv = dinv[v];
    int start = offs[v];
    int deg   = cnt[v];
    const float2* h2 = (const float2*)h;

    float2 self = h2[(size_t)v * 64 + lane];
    float2 acc;
    acc.x = dv * self.x;      // self-loop term (gets *dv again at the end)
    acc.y = dv * self.y;

    for (int base = 0; base < deg; base += 64) {
        int m = min(64, deg - base);
        int s = 0; float w = 0.f;
        if (lane < m) { s = esrc[start + base + lane]; w = dinv[s]; }
        int j = 0;
        for (; j + 1 < m; j += 2) {
            int   s0 = __shfl(s, j),     s1 = __shfl(s, j + 1);
            float w0 = __shfl(w, j),     w1 = __shfl(w, j + 1);
            float2 a0 = h2[(size_t)s0 * 64 + lane];
            float2 a1 = h2[(size_t)s1 * 64 + lane];
            acc.x = fmaf(w0, a0.x, acc.x); acc.y = fmaf(w0, a0.y, acc.y);
            acc.x = fmaf(w1, a1.x, acc.x); acc.y = fmaf(w1, a1.y, acc.y);
        }
        if (j < m) {
            int   s0 = __shfl(s, j);
            float w0 = __shfl(w, j);
            float2 a0 = h2[(size_t)s0 * 64 + lane];
            acc.x = fmaf(w0, a0.x, acc.x); acc.y = fmaf(w0, a0.y, acc.y);
        }
    }
    acc.x *= dv; acc.y *= dv;
    if (bias) { acc.x += bias[lane * 2]; acc.y += bias[lane * 2 + 1]; }
    if (do_relu) { acc.x = fmaxf(acc.x, 0.f); acc.y = fmaxf(acc.y, 0.f); }
    ((float2*)out)[(size_t)v * 64 + lane] = acc;
}

// ---- GEMM1: H = X @ W  (n x 128) @ (128 x 128), fp32 ----
// block = 256 thr, tile = 64 nodes x 128 cols; x-tile transposed in LDS so
// inner-loop LDS reads are per-half-wave broadcasts of float4.
__global__ __launch_bounds__(256) void k_gemm1(
    const float* __restrict__ X, const float* __restrict__ W,
    float* __restrict__ H, int n)
{
    __shared__ float xT[128][68];   // pad 68: 16B-aligned float4 at [k][8*ty]
    int tid = threadIdx.x;
    int tx = tid & 31, ty = tid >> 5;
    int nbase = blockIdx.x * 64;
    #pragma unroll
    for (int r = 0; r < 8; ++r) {
        int nl = r * 8 + ty;
        int node = nbase + nl;
        int k4 = tx * 4;
        float4 v = make_float4(0.f, 0.f, 0.f, 0.f);
        if (node < n) v = *(const float4*)&X[(size_t)node * 128 + k4];
        xT[k4 + 0][nl] = v.x; xT[k4 + 1][nl] = v.y;
        xT[k4 + 2][nl] = v.z; xT[k4 + 3][nl] = v.w;
    }
    __syncthreads();

    float acc[8][4];
    #pragma unroll
    for (int i = 0; i < 8; ++i)
        #pragma unroll
        for (int c = 0; c < 4; ++c) acc[i][c] = 0.f;

    int j0 = tx * 4;
    int n0 = ty * 8;
    #pragma unroll 4
    for (int k = 0; k < 128; ++k) {
        float4 wv = *(const float4*)&W[k * 128 + j0];
        float4 xa = *(const float4*)&xT[k][n0];
        float4 xb = *(const float4*)&xT[k][n0 + 4];
        float xv[8] = {xa.x, xa.y, xa.z, xa.w, xb.x, xb.y, xb.z, xb.w};
        float wc[4] = {wv.x, wv.y, wv.z, wv.w};
        #pragma unroll
        for (int i = 0; i < 8; ++i)
            #pragma unroll
            for (int c = 0; c < 4; ++c)
                acc[i][c] = fmaf(xv[i], wc[c], acc[i][c]);
    }
    #pragma unroll
    for (int i = 0; i < 8; ++i) {
        int node = nbase + n0 + i;
        if (node < n) {
            float4 o = make_float4(acc[i][0], acc[i][1], acc[i][2], acc[i][3]);
            *(float4*)&H[(size_t)node * 128 + j0] = o;
        }
    }
}

// ---- GEMM2: out = G @ [Wmu | Wls] + [bmu | bls], split-written to d_out ----
__global__ __launch_bounds__(256) void k_gemm2(
    const float* __restrict__ G,
    const float* __restrict__ Wmu, const float* __restrict__ Wls,
    const float* __restrict__ bmu, const float* __restrict__ bls,
    float* __restrict__ out, int n)
{
    __shared__ float xT[128][68];
    int tid = threadIdx.x;
    int tx = tid & 31, ty = tid >> 5;
    int nbase = blockIdx.x * 64;
    #pragma unroll
    for (int r = 0; r < 8; ++r) {
        int nl = r * 8 + ty;
        int node = nbase + nl;
        int k4 = tx * 4;
        float4 v = make_float4(0.f, 0.f, 0.f, 0.f);
        if (node < n) v = *(const float4*)&G[(size_t)node * 128 + k4];
        xT[k4 + 0][nl] = v.x; xT[k4 + 1][nl] = v.y;
        xT[k4 + 2][nl] = v.z; xT[k4 + 3][nl] = v.w;
    }
    __syncthreads();

    float acc[8][4];
    #pragma unroll
    for (int i = 0; i < 8; ++i)
        #pragma unroll
        for (int c = 0; c < 4; ++c) acc[i][c] = 0.f;

    const float* Wh = (tx < 16) ? Wmu : Wls;
    int jj = (tx & 15) * 4;      // column within the 64-wide half
    int n0 = ty * 8;
    #pragma unroll 4
    for (int k = 0; k < 128; ++k) {
        float4 wv = *(const float4*)&Wh[k * 64 + jj];
        float4 xa = *(const float4*)&xT[k][n0];
        float4 xb = *(const float4*)&xT[k][n0 + 4];
        float xv[8] = {xa.x, xa.y, xa.z, xa.w, xb.x, xb.y, xb.z, xb.w};
        float wc[4] = {wv.x, wv.y, wv.z, wv.w};
        #pragma unroll
        for (int i = 0; i < 8; ++i)
            #pragma unroll
            for (int c = 0; c < 4; ++c)
                acc[i][c] = fmaf(xv[i], wc[c], acc[i][c]);
    }
    const float* bh = (tx < 16) ? bmu : bls;
    float4 bb = *(const float4*)&bh[jj];
    size_t halfoff = (tx < 16) ? (size_t)0 : (size_t)n * 64;
    #pragma unroll
    for (int i = 0; i < 8; ++i) {
        int node = nbase + n0 + i;
        if (node < n) {
            float4 o = make_float4(acc[i][0] + bb.x, acc[i][1] + bb.y,
                                   acc[i][2] + bb.z, acc[i][3] + bb.w);
            *(float4*)&out[halfoff + (size_t)node * 64 + jj] = o;
        }
    }
}

extern "C" void kernel_launch(void* const* d_in, const int* in_sizes, int n_in,
                              void* d_out, int out_size, void* d_ws, size_t ws_size,
                              hipStream_t stream) {
    const float* x   = (const float*)d_in[0];
    const int*   ei  = (const int*)d_in[1];
    // d_in[2] = batch (unused: classifier disabled in reference)
    const float* W1  = (const float*)d_in[3];
    const float* b1  = (const float*)d_in[4];
    const float* Wmu = (const float*)d_in[5];
    const float* bmu = (const float*)d_in[6];
    const float* Wls = (const float*)d_in[7];
    const float* bls = (const float*)d_in[8];
    float* out = (float*)d_out;

    int n = in_sizes[0] / 128;   // 100000
    int e = in_sizes[1] / 2;     // 1600000
    const int* erow = ei;        // sources
    const int* ecol = ei + e;    // targets

    // workspace carve-up (re-poisoned every call; every byte we read is
    // rewritten by an earlier kernel in this same launch)
    char* p = (char*)d_ws;
    auto alloc = [&](size_t bytes) -> char* {
        char* q = p; p += (bytes + 255) & ~(size_t)255; return q;
    };
    int*   cnt    = (int*)  alloc((size_t)n * 4);
    int*   offs   = (int*)  alloc((size_t)n * 4);
    int*   cursor = (int*)  alloc((size_t)n * 4);
    int*   bsum   = (int*)  alloc(512);
    int*   bbase  = (int*)  alloc(512);
    float* dinv   = (float*)alloc((size_t)n * 4);
    int*   esrc   = (int*)  alloc((size_t)e * 4);
    float* h      = (float*)alloc((size_t)n * 128 * 4);
    float* h1     = (float*)alloc((size_t)n * 128 * 4);
    float* g      = h;   // h is dead after prop1 -> reuse for g

    int nb = (n + 1023) / 1024;          // <=128 for n<=131072

    k_zero_int<<<(n + 255) / 256, 256, 0, stream>>>(cnt, n);
    k_count<<<(e + 255) / 256, 256, 0, stream>>>(ecol, e, cnt);
    k_dinv<<<(n + 255) / 256, 256, 0, stream>>>(cnt, dinv, n);
    k_bsum<<<nb, 256, 0, stream>>>(cnt, n, bsum);
    k_scan_bsum<<<1, 128, 0, stream>>>(bsum, nb, bbase);
    k_scan_local<<<nb, 256, 0, stream>>>(cnt, bbase, offs, cursor, n);
    k_fill<<<(e + 255) / 256, 256, 0, stream>>>(erow, ecol, e, cursor, esrc);

    k_gemm1<<<(n + 63) / 64, 256, 0, stream>>>(x, W1, h, n);
    k_prop<<<(n + 3) / 4, 256, 0, stream>>>(h, dinv, offs, cnt, esrc, h1, b1, 1, n);
    k_prop<<<(n + 3) / 4, 256, 0, stream>>>(h1, dinv, offs, cnt, esrc, g, nullptr, 0, n);
    k_gemm2<<<(n + 63) / 64, 256, 0, stream>>>(g, Wmu, Wls, bmu, bls, out, n);
}

// Round 2
// 574.816 us; speedup vs baseline: 1.1261x; 1.1261x over previous
//
#include <hip/hip_runtime.h>
#include <hip/hip_bf16.h>

// ---------------------------------------------------------------------------
// GCN encoder: h1 = relu(P (x W1) + b1); mu = P (h1 Wmu) + bmu; ls likewise.
// P = D^-1/2 (A + I) D^-1/2 with in-degree-based D (cols are targets).
// CSR build is a two-pass bucket sort (512-target buckets) so the edge
// permutation scatter happens in LDS / block-private L2 segments instead of
// random 4B global writes (R1: k_fill had 16x write amplification, 105 MB
// WRITE_SIZE for a 6.4 MB array, 130 us).
// ---------------------------------------------------------------------------

#define BW_SH   9                 // bucket width = 512 targets
#define BW      (1 << BW_SH)
#define NBUCK_MAX 256             // supports n <= 131072 (bucket id fits u8)
#define EPB     12288             // edges per k_bucket block (48 KB LDS items)
#define FCAP    10240             // k_fill2 LDS staging capacity (mean ~8.2K)

__global__ void k_zero_int(int* __restrict__ p, int n) {
    int i = blockIdx.x * blockDim.x + threadIdx.x;
    if (i < n) p[i] = 0;
}

__global__ void k_count(const int* __restrict__ col, int e, int* __restrict__ cnt) {
    int i = blockIdx.x * blockDim.x + threadIdx.x;
    if (i < e) atomicAdd(&cnt[col[i]], 1);
}

__global__ void k_dinv(const int* __restrict__ cnt, float* __restrict__ dinv, int n) {
    int i = blockIdx.x * blockDim.x + threadIdx.x;
    if (i < n) dinv[i] = 1.0f / sqrtf((float)(cnt[i] + 1));   // +1 self loop; > 0
}

// ---- hierarchical exclusive scan of cnt[] -> offs[] (chunk = 1024) ----
__global__ void k_bsum(const int* __restrict__ cnt, int n, int* __restrict__ bsum) {
    __shared__ int sh[256];
    int b = blockIdx.x, tid = threadIdx.x;
    int i0 = b * 1024 + tid * 4;
    int s = 0;
    if (i0 + 3 < n) {
        s = cnt[i0] + cnt[i0 + 1] + cnt[i0 + 2] + cnt[i0 + 3];
    } else {
        for (int c = 0; c < 4; ++c) if (i0 + c < n) s += cnt[i0 + c];
    }
    sh[tid] = s; __syncthreads();
    for (int d = 128; d > 0; d >>= 1) {
        if (tid < d) sh[tid] += sh[tid + d];
        __syncthreads();
    }
    if (tid == 0) bsum[b] = sh[0];
}

__global__ void k_scan_bsum(const int* __restrict__ bsum, int nb, int* __restrict__ bbase) {
    __shared__ int sh[128];
    int t = threadIdx.x;
    int v = (t < nb) ? bsum[t] : 0;
    sh[t] = v; __syncthreads();
    for (int d = 1; d < 128; d <<= 1) {
        int u = (t >= d) ? sh[t - d] : 0;
        __syncthreads();
        sh[t] += u;
        __syncthreads();
    }
    if (t < nb) bbase[t] = sh[t] - v;   // exclusive
}

__global__ void k_scan_local(const int* __restrict__ cnt, const int* __restrict__ bbase,
                             int* __restrict__ offs, int n) {
    __shared__ int sh[256];
    int b = blockIdx.x, tid = threadIdx.x;
    int i0 = b * 1024 + tid * 4;
    int v0 = (i0 + 0 < n) ? cnt[i0 + 0] : 0;
    int v1 = (i0 + 1 < n) ? cnt[i0 + 1] : 0;
    int v2 = (i0 + 2 < n) ? cnt[i0 + 2] : 0;
    int v3 = (i0 + 3 < n) ? cnt[i0 + 3] : 0;
    int ts = v0 + v1 + v2 + v3;
    sh[tid] = ts; __syncthreads();
    for (int d = 1; d < 256; d <<= 1) {
        int t = (tid >= d) ? sh[tid - d] : 0;
        __syncthreads();
        sh[tid] += t;
        __syncthreads();
    }
    int excl = sh[tid] - ts + bbase[b];
    int o0 = excl, o1 = o0 + v0, o2 = o1 + v1, o3 = o2 + v2;
    if (i0 + 0 < n) offs[i0 + 0] = o0;
    if (i0 + 1 < n) offs[i0 + 1] = o1;
    if (i0 + 2 < n) offs[i0 + 2] = o2;
    if (i0 + 3 < n) offs[i0 + 3] = o3;
}

// gcur[b] = start of bucket b's segment in pairs[] (= offs[b*512])
__global__ void k_gcur(const int* __restrict__ offs, int* __restrict__ gcur, int nbuck) {
    int t = threadIdx.x;
    if (t < nbuck) gcur[t] = offs[t << BW_SH];
}

// ---- pass 1: bucket edges by target/512 into bucket-contiguous pairs[] ----
// Each block reserves per-bucket global segments (one atomicAdd per bucket),
// then scatters items into its PRIVATE segments -> no cross-XCD line churn.
__global__ __launch_bounds__(256) void k_bucket(
    const int* __restrict__ row, const int* __restrict__ col, int e,
    int* __restrict__ gcur, int* __restrict__ pairs)
{
    __shared__ int items[EPB];                 // 48 KB
    __shared__ unsigned char bkt[EPB];         // 12 KB
    __shared__ int hcnt[NBUCK_MAX];
    __shared__ int lbase[NBUCK_MAX];
    int tid = threadIdx.x;
    int e0 = blockIdx.x * EPB;
    int e1 = min(e, e0 + EPB);
    int m = e1 - e0;
    for (int b = tid; b < NBUCK_MAX; b += 256) hcnt[b] = 0;
    __syncthreads();
    for (int i = tid; i < m; i += 256) {
        int s = row[e0 + i];
        int d = col[e0 + i];
        items[i] = (s << BW_SH) | (d & (BW - 1));
        int b = d >> BW_SH;
        bkt[i] = (unsigned char)b;
        atomicAdd(&hcnt[b], 1);
    }
    __syncthreads();
    for (int b = tid; b < NBUCK_MAX; b += 256)
        lbase[b] = hcnt[b] ? atomicAdd(&gcur[b], hcnt[b]) : 0;
    __syncthreads();
    for (int i = tid; i < m; i += 256) {
        int pos = atomicAdd(&lbase[bkt[i]], 1);
        pairs[pos] = items[i];
    }
}

// ---- pass 2: per-bucket LDS scatter -> fully coalesced esrc writes ----
__global__ __launch_bounds__(256) void k_fill2(
    const int* __restrict__ offs, const int* __restrict__ pairs,
    int* __restrict__ esrc, int n, int e)
{
    __shared__ int lesrc[FCAP];   // 40 KB
    __shared__ int lcur[BW];      // 2 KB
    int b = blockIdx.x, tid = threadIdx.x;
    int t0 = b << BW_SH;
    int t1 = min(n, t0 + BW);
    int cbase = offs[t0];
    int cend  = (t1 == n) ? e : offs[t1];
    int m = cend - cbase;
    for (int t = tid; t < t1 - t0; t += 256)
        lcur[t] = offs[t0 + t] - cbase;
    __syncthreads();
    if (m <= FCAP) {
        for (int i = tid; i < m; i += 256) {
            int item = pairs[cbase + i];
            int pos = atomicAdd(&lcur[item & (BW - 1)], 1);
            lesrc[pos] = item >> BW_SH;
        }
        __syncthreads();
        for (int i = tid; i < m; i += 256)
            esrc[cbase + i] = lesrc[i];
    } else {   // safety fallback (statistically unreachable for this graph)
        for (int i = tid; i < m; i += 256) {
            int item = pairs[cbase + i];
            int pos = atomicAdd(&lcur[item & (BW - 1)], 1);
            esrc[cbase + pos] = item >> BW_SH;
        }
    }
}

// ---- propagation: one wave per node, 2 feats/lane (128 feats) ----
// out[v] = dinv[v] * ( sum_{e: col=v} dinv[src]*h[src] + dinv[v]*h[v] ) (+bias)(relu)
__global__ __launch_bounds__(256) void k_prop(
    const float* __restrict__ h, const float* __restrict__ dinv,
    const int* __restrict__ offs, const int* __restrict__ cnt,
    const int* __restrict__ esrc, float* __restrict__ out,
    const float* __restrict__ bias, int do_relu, int n)
{
    int wid  = (blockIdx.x * blockDim.x + threadIdx.x) >> 6;
    int lane = threadIdx.x & 63;
    if (wid >= n) return;
    int v = wid;
    float dv = dinv[v];
    int start = offs[v];
    int deg   = cnt[v];
    const float2* h2 = (const float2*)h;

    float2 self = h2[(size_t)v * 64 + lane];
    float2 acc;
    acc.x = dv * self.x;      // self-loop term (gets *dv again at the end)
    acc.y = dv * self.y;

    for (int base = 0; base < deg; base += 64) {
        int m = min(64, deg - base);
        int s = 0; float w = 0.f;
        if (lane < m) { s = esrc[start + base + lane]; w = dinv[s]; }
        int j = 0;
        for (; j + 3 < m; j += 4) {   // 4 gathers in flight per wave
            int   s0 = __shfl(s, j),     s1 = __shfl(s, j + 1);
            int   s2 = __shfl(s, j + 2), s3 = __shfl(s, j + 3);
            float w0 = __shfl(w, j),     w1 = __shfl(w, j + 1);
            float w2 = __shfl(w, j + 2), w3 = __shfl(w, j + 3);
            float2 a0 = h2[(size_t)s0 * 64 + lane];
            float2 a1 = h2[(size_t)s1 * 64 + lane];
            float2 a2 = h2[(size_t)s2 * 64 + lane];
            float2 a3 = h2[(size_t)s3 * 64 + lane];
            acc.x = fmaf(w0, a0.x, acc.x); acc.y = fmaf(w0, a0.y, acc.y);
            acc.x = fmaf(w1, a1.x, acc.x); acc.y = fmaf(w1, a1.y, acc.y);
            acc.x = fmaf(w2, a2.x, acc.x); acc.y = fmaf(w2, a2.y, acc.y);
            acc.x = fmaf(w3, a3.x, acc.x); acc.y = fmaf(w3, a3.y, acc.y);
        }
        for (; j < m; ++j) {
            int   s0 = __shfl(s, j);
            float w0 = __shfl(w, j);
            float2 a0 = h2[(size_t)s0 * 64 + lane];
            acc.x = fmaf(w0, a0.x, acc.x); acc.y = fmaf(w0, a0.y, acc.y);
        }
    }
    acc.x *= dv; acc.y *= dv;
    if (bias) { acc.x += bias[lane * 2]; acc.y += bias[lane * 2 + 1]; }
    if (do_relu) { acc.x = fmaxf(acc.x, 0.f); acc.y = fmaxf(acc.y, 0.f); }
    ((float2*)out)[(size_t)v * 64 + lane] = acc;
}

// ---- GEMM1: H = X @ W  (n x 128) @ (128 x 128), fp32 ----
__global__ __launch_bounds__(256) void k_gemm1(
    const float* __restrict__ X, const float* __restrict__ W,
    float* __restrict__ H, int n)
{
    __shared__ float xT[128][68];
    int tid = threadIdx.x;
    int tx = tid & 31, ty = tid >> 5;
    int nbase = blockIdx.x * 64;
    #pragma unroll
    for (int r = 0; r < 8; ++r) {
        int nl = r * 8 + ty;
        int node = nbase + nl;
        int k4 = tx * 4;
        float4 v = make_float4(0.f, 0.f, 0.f, 0.f);
        if (node < n) v = *(const float4*)&X[(size_t)node * 128 + k4];
        xT[k4 + 0][nl] = v.x; xT[k4 + 1][nl] = v.y;
        xT[k4 + 2][nl] = v.z; xT[k4 + 3][nl] = v.w;
    }
    __syncthreads();

    float acc[8][4];
    #pragma unroll
    for (int i = 0; i < 8; ++i)
        #pragma unroll
        for (int c = 0; c < 4; ++c) acc[i][c] = 0.f;

    int j0 = tx * 4;
    int n0 = ty * 8;
    #pragma unroll 4
    for (int k = 0; k < 128; ++k) {
        float4 wv = *(const float4*)&W[k * 128 + j0];
        float4 xa = *(const float4*)&xT[k][n0];
        float4 xb = *(const float4*)&xT[k][n0 + 4];
        float xv[8] = {xa.x, xa.y, xa.z, xa.w, xb.x, xb.y, xb.z, xb.w};
        float wc[4] = {wv.x, wv.y, wv.z, wv.w};
        #pragma unroll
        for (int i = 0; i < 8; ++i)
            #pragma unroll
            for (int c = 0; c < 4; ++c)
                acc[i][c] = fmaf(xv[i], wc[c], acc[i][c]);
    }
    #pragma unroll
    for (int i = 0; i < 8; ++i) {
        int node = nbase + n0 + i;
        if (node < n) {
            float4 o = make_float4(acc[i][0], acc[i][1], acc[i][2], acc[i][3]);
            *(float4*)&H[(size_t)node * 128 + j0] = o;
        }
    }
}

// ---- GEMM2: out = G @ [Wmu | Wls] + [bmu | bls], split-written to d_out ----
__global__ __launch_bounds__(256) void k_gemm2(
    const float* __restrict__ G,
    const float* __restrict__ Wmu, const float* __restrict__ Wls,
    const float* __restrict__ bmu, const float* __restrict__ bls,
    float* __restrict__ out, int n)
{
    __shared__ float xT[128][68];
    int tid = threadIdx.x;
    int tx = tid & 31, ty = tid >> 5;
    int nbase = blockIdx.x * 64;
    #pragma unroll
    for (int r = 0; r < 8; ++r) {
        int nl = r * 8 + ty;
        int node = nbase + nl;
        int k4 = tx * 4;
        float4 v = make_float4(0.f, 0.f, 0.f, 0.f);
        if (node < n) v = *(const float4*)&G[(size_t)node * 128 + k4];
        xT[k4 + 0][nl] = v.x; xT[k4 + 1][nl] = v.y;
        xT[k4 + 2][nl] = v.z; xT[k4 + 3][nl] = v.w;
    }
    __syncthreads();

    float acc[8][4];
    #pragma unroll
    for (int i = 0; i < 8; ++i)
        #pragma unroll
        for (int c = 0; c < 4; ++c) acc[i][c] = 0.f;

    const float* Wh = (tx < 16) ? Wmu : Wls;
    int jj = (tx & 15) * 4;
    int n0 = ty * 8;
    #pragma unroll 4
    for (int k = 0; k < 128; ++k) {
        float4 wv = *(const float4*)&Wh[k * 64 + jj];
        float4 xa = *(const float4*)&xT[k][n0];
        float4 xb = *(const float4*)&xT[k][n0 + 4];
        float xv[8] = {xa.x, xa.y, xa.z, xa.w, xb.x, xb.y, xb.z, xb.w};
        float wc[4] = {wv.x, wv.y, wv.z, wv.w};
        #pragma unroll
        for (int i = 0; i < 8; ++i)
            #pragma unroll
            for (int c = 0; c < 4; ++c)
                acc[i][c] = fmaf(xv[i], wc[c], acc[i][c]);
    }
    const float* bh = (tx < 16) ? bmu : bls;
    float4 bb = *(const float4*)&bh[jj];
    size_t halfoff = (tx < 16) ? (size_t)0 : (size_t)n * 64;
    #pragma unroll
    for (int i = 0; i < 8; ++i) {
        int node = nbase + n0 + i;
        if (node < n) {
            float4 o = make_float4(acc[i][0] + bb.x, acc[i][1] + bb.y,
                                   acc[i][2] + bb.z, acc[i][3] + bb.w);
            *(float4*)&out[halfoff + (size_t)node * 64 + jj] = o;
        }
    }
}

extern "C" void kernel_launch(void* const* d_in, const int* in_sizes, int n_in,
                              void* d_out, int out_size, void* d_ws, size_t ws_size,
                              hipStream_t stream) {
    const float* x   = (const float*)d_in[0];
    const int*   ei  = (const int*)d_in[1];
    // d_in[2] = batch (unused: classifier disabled in reference)
    const float* W1  = (const float*)d_in[3];
    const float* b1  = (const float*)d_in[4];
    const float* Wmu = (const float*)d_in[5];
    const float* bmu = (const float*)d_in[6];
    const float* Wls = (const float*)d_in[7];
    const float* bls = (const float*)d_in[8];
    float* out = (float*)d_out;

    int n = in_sizes[0] / 128;   // 100000
    int e = in_sizes[1] / 2;     // 1600000
    const int* erow = ei;        // sources
    const int* ecol = ei + e;    // targets
    int nbuck = (n + BW - 1) >> BW_SH;   // 196

    char* p = (char*)d_ws;
    auto alloc = [&](size_t bytes) -> char* {
        char* q = p; p += (bytes + 255) & ~(size_t)255; return q;
    };
    int*   cnt    = (int*)  alloc((size_t)n * 4);
    int*   offs   = (int*)  alloc((size_t)n * 4);
    int*   bsum   = (int*)  alloc(512);
    int*   bbase  = (int*)  alloc(512);
    int*   gcur   = (int*)  alloc(NBUCK_MAX * 4);
    float* dinv   = (float*)alloc((size_t)n * 4);
    int*   esrc   = (int*)  alloc((size_t)e * 4);
    float* h      = (float*)alloc((size_t)n * 128 * 4);
    float* h1     = (float*)alloc((size_t)n * 128 * 4);
    int*   pairs  = (int*)h;   // pairs[] dead before gemm1 writes h
    float* g      = h;         // h dead after prop1 -> reuse for g

    int nb = (n + 1023) / 1024;

    k_zero_int<<<(n + 255) / 256, 256, 0, stream>>>(cnt, n);
    k_count<<<(e + 255) / 256, 256, 0, stream>>>(ecol, e, cnt);
    k_dinv<<<(n + 255) / 256, 256, 0, stream>>>(cnt, dinv, n);
    k_bsum<<<nb, 256, 0, stream>>>(cnt, n, bsum);
    k_scan_bsum<<<1, 128, 0, stream>>>(bsum, nb, bbase);
    k_scan_local<<<nb, 256, 0, stream>>>(cnt, bbase, offs, n);
    k_gcur<<<1, 256, 0, stream>>>(offs, gcur, nbuck);
    k_bucket<<<(e + EPB - 1) / EPB, 256, 0, stream>>>(erow, ecol, e, gcur, pairs);
    k_fill2<<<nbuck, 256, 0, stream>>>(offs, pairs, esrc, n, e);

    k_gemm1<<<(n + 63) / 64, 256, 0, stream>>>(x, W1, h, n);
    k_prop<<<(n + 3) / 4, 256, 0, stream>>>(h, dinv, offs, cnt, esrc, h1, b1, 1, n);
    k_prop<<<(n + 3) / 4, 256, 0, stream>>>(h1, dinv, offs, cnt, esrc, g, nullptr, 0, n);
    k_gemm2<<<(n + 63) / 64, 256, 0, stream>>>(g, Wmu, Wls, bmu, bls, out, n);
}

// Round 3
// 456.738 us; speedup vs baseline: 1.4172x; 1.2585x over previous
//
#include <hip/hip_runtime.h>
#include <hip/hip_bf16.h>

// ---------------------------------------------------------------------------
// GCN encoder: h1 = relu(P (x W1) + b1); mu = P (h1 Wmu) + bmu; ls likewise.
// P = D^-1/2 (A + I) D^-1/2, in-degree D. CSR via two-pass bucket sort (R2).
// R3: feature tables h and h1 stored as bf16 -> gather traffic halved
// (R2: k_prop FETCH 417 MB, 123 us each, pure memory-bound). Propagation
// processes 2 edges per wave (half-wave per 256B row, uint2/lane loads).
// g (=P h1) stays fp32: read once, keeps numeric margin for the final GEMM.
// ---------------------------------------------------------------------------

#define BW_SH   9                 // bucket width = 512 targets
#define BW      (1 << BW_SH)
#define NBUCK_MAX 256             // supports n <= 131072
#define EPB     12288             // edges per k_bucket block
#define FCAP    10240             // k_fill2 LDS staging capacity

__device__ __forceinline__ unsigned bf16rne(float f) {   // fp32 -> bf16 bits (RNE)
    unsigned u = __float_as_uint(f);
    return (u + 0x7fffu + ((u >> 16) & 1u)) >> 16;
}
__device__ __forceinline__ float bflo(unsigned u) { return __uint_as_float(u << 16); }
__device__ __forceinline__ float bfhi(unsigned u) { return __uint_as_float(u & 0xffff0000u); }

__global__ void k_zero_int(int* __restrict__ p, int n) {
    int i = blockIdx.x * blockDim.x + threadIdx.x;
    if (i < n) p[i] = 0;
}

__global__ void k_count(const int* __restrict__ col, int e, int* __restrict__ cnt) {
    int i = blockIdx.x * blockDim.x + threadIdx.x;
    if (i < e) atomicAdd(&cnt[col[i]], 1);
}

// ---- hierarchical exclusive scan of cnt[] -> offs[] (chunk = 1024) ----
__global__ void k_bsum(const int* __restrict__ cnt, int n, int* __restrict__ bsum) {
    __shared__ int sh[256];
    int b = blockIdx.x, tid = threadIdx.x;
    int i0 = b * 1024 + tid * 4;
    int s = 0;
    if (i0 + 3 < n) {
        s = cnt[i0] + cnt[i0 + 1] + cnt[i0 + 2] + cnt[i0 + 3];
    } else {
        for (int c = 0; c < 4; ++c) if (i0 + c < n) s += cnt[i0 + c];
    }
    sh[tid] = s; __syncthreads();
    for (int d = 128; d > 0; d >>= 1) {
        if (tid < d) sh[tid] += sh[tid + d];
        __syncthreads();
    }
    if (tid == 0) bsum[b] = sh[0];
}

__global__ void k_scan_bsum(const int* __restrict__ bsum, int nb, int* __restrict__ bbase) {
    __shared__ int sh[128];
    int t = threadIdx.x;
    int v = (t < nb) ? bsum[t] : 0;
    sh[t] = v; __syncthreads();
    for (int d = 1; d < 128; d <<= 1) {
        int u = (t >= d) ? sh[t - d] : 0;
        __syncthreads();
        sh[t] += u;
        __syncthreads();
    }
    if (t < nb) bbase[t] = sh[t] - v;   // exclusive
}

// scan within chunk + emit dinv and per-bucket gcur (folds 2 kernels in)
__global__ void k_scan_local(const int* __restrict__ cnt, const int* __restrict__ bbase,
                             int* __restrict__ offs, float* __restrict__ dinv,
                             int* __restrict__ gcur, int n) {
    __shared__ int sh[256];
    int b = blockIdx.x, tid = threadIdx.x;
    int i0 = b * 1024 + tid * 4;
    int v0 = (i0 + 0 < n) ? cnt[i0 + 0] : 0;
    int v1 = (i0 + 1 < n) ? cnt[i0 + 1] : 0;
    int v2 = (i0 + 2 < n) ? cnt[i0 + 2] : 0;
    int v3 = (i0 + 3 < n) ? cnt[i0 + 3] : 0;
    int ts = v0 + v1 + v2 + v3;
    sh[tid] = ts; __syncthreads();
    for (int d = 1; d < 256; d <<= 1) {
        int t = (tid >= d) ? sh[tid - d] : 0;
        __syncthreads();
        sh[tid] += t;
        __syncthreads();
    }
    int excl = sh[tid] - ts + bbase[b];
    int o[4] = {excl, excl + v0, excl + v0 + v1, excl + v0 + v1 + v2};
    int vv[4] = {v0, v1, v2, v3};
    #pragma unroll
    for (int c = 0; c < 4; ++c) {
        int idx = i0 + c;
        if (idx < n) {
            offs[idx] = o[c];
            dinv[idx] = 1.0f / sqrtf((float)(vv[c] + 1));
            if ((idx & (BW - 1)) == 0) gcur[idx >> BW_SH] = o[c];
        }
    }
}

// ---- pass 1: bucket edges by target/512 into bucket-contiguous pairs[] ----
__global__ __launch_bounds__(256) void k_bucket(
    const int* __restrict__ row, const int* __restrict__ col, int e,
    int* __restrict__ gcur, int* __restrict__ pairs)
{
    __shared__ int items[EPB];
    __shared__ unsigned char bkt[EPB];
    __shared__ int hcnt[NBUCK_MAX];
    __shared__ int lbase[NBUCK_MAX];
    int tid = threadIdx.x;
    int e0 = blockIdx.x * EPB;
    int e1 = min(e, e0 + EPB);
    int m = e1 - e0;
    for (int b = tid; b < NBUCK_MAX; b += 256) hcnt[b] = 0;
    __syncthreads();
    for (int i = tid; i < m; i += 256) {
        int s = row[e0 + i];
        int d = col[e0 + i];
        items[i] = (s << BW_SH) | (d & (BW - 1));
        int b = d >> BW_SH;
        bkt[i] = (unsigned char)b;
        atomicAdd(&hcnt[b], 1);
    }
    __syncthreads();
    for (int b = tid; b < NBUCK_MAX; b += 256)
        lbase[b] = hcnt[b] ? atomicAdd(&gcur[b], hcnt[b]) : 0;
    __syncthreads();
    for (int i = tid; i < m; i += 256) {
        int pos = atomicAdd(&lbase[bkt[i]], 1);
        pairs[pos] = items[i];
    }
}

// ---- pass 2: per-bucket LDS scatter -> coalesced esrc writes ----
__global__ __launch_bounds__(256) void k_fill2(
    const int* __restrict__ offs, const int* __restrict__ pairs,
    int* __restrict__ esrc, int n, int e)
{
    __shared__ int lesrc[FCAP];
    __shared__ int lcur[BW];
    int b = blockIdx.x, tid = threadIdx.x;
    int t0 = b << BW_SH;
    int t1 = min(n, t0 + BW);
    int cbase = offs[t0];
    int cend  = (t1 == n) ? e : offs[t1];
    int m = cend - cbase;
    for (int t = tid; t < t1 - t0; t += 256)
        lcur[t] = offs[t0 + t] - cbase;
    __syncthreads();
    if (m <= FCAP) {
        for (int i = tid; i < m; i += 256) {
            int item = pairs[cbase + i];
            int pos = atomicAdd(&lcur[item & (BW - 1)], 1);
            lesrc[pos] = item >> BW_SH;
        }
        __syncthreads();
        for (int i = tid; i < m; i += 256)
            esrc[cbase + i] = lesrc[i];
    } else {
        for (int i = tid; i < m; i += 256) {
            int item = pairs[cbase + i];
            int pos = atomicAdd(&lcur[item & (BW - 1)], 1);
            esrc[cbase + pos] = item >> BW_SH;
        }
    }
}

// ---- propagation over bf16 table: one wave per node, 2 edges in parallel ----
// Row = 128 bf16 = 256 B = 32 lanes x uint2. half = lane>>5 handles edge j+half;
// lane covers feats 4*fl..4*fl+3 (fl = lane&31). Halves combined via shfl_xor.
// out = dinv[v]*(sum dinv[s]*h[s] + dinv[v]*h[v]) (+bias, relu -> bf16 | fp32)
__global__ __launch_bounds__(256) void k_prop_bf(
    const unsigned* __restrict__ hbf, const float* __restrict__ dinv,
    const int* __restrict__ offs, const int* __restrict__ cnt,
    const int* __restrict__ esrc,
    unsigned* __restrict__ out_bf,      // non-null: +bias, relu, bf16 write
    float* __restrict__ out_f32,        // else: raw fp32 write
    const float* __restrict__ bias, int n)
{
    int wid  = (blockIdx.x * blockDim.x + threadIdx.x) >> 6;
    if (wid >= n) return;
    int lane = threadIdx.x & 63;
    int half = lane >> 5;
    int fl   = lane & 31;
    int v = wid;
    float dv = dinv[v];
    int start = offs[v];
    int deg   = cnt[v];
    const uint2* rows = (const uint2*)hbf;   // row r at rows[r*32 + fl]

    float a0 = 0.f, a1 = 0.f, a2 = 0.f, a3 = 0.f;
    if (half == 0) {   // self-loop term on the low half
        uint2 r = rows[(size_t)v * 32 + fl];
        a0 = dv * bflo(r.x); a1 = dv * bfhi(r.x);
        a2 = dv * bflo(r.y); a3 = dv * bfhi(r.y);
    }

    for (int base = 0; base < deg; base += 64) {
        int m = min(64, deg - base);
        int s = 0; float w = 0.f;
        if (lane < m) { s = esrc[start + base + lane]; w = dinv[s]; }
        int j = 0;
        for (; j + 8 <= m; j += 8) {     // 4 row-loads in flight per wave
            int   s0 = __shfl(s, j + 0 + half), s1 = __shfl(s, j + 2 + half);
            int   s2 = __shfl(s, j + 4 + half), s3 = __shfl(s, j + 6 + half);
            float w0 = __shfl(w, j + 0 + half), w1 = __shfl(w, j + 2 + half);
            float w2 = __shfl(w, j + 4 + half), w3 = __shfl(w, j + 6 + half);
            uint2 r0 = rows[(size_t)s0 * 32 + fl];
            uint2 r1 = rows[(size_t)s1 * 32 + fl];
            uint2 r2 = rows[(size_t)s2 * 32 + fl];
            uint2 r3 = rows[(size_t)s3 * 32 + fl];
            a0 = fmaf(w0, bflo(r0.x), a0); a1 = fmaf(w0, bfhi(r0.x), a1);
            a2 = fmaf(w0, bflo(r0.y), a2); a3 = fmaf(w0, bfhi(r0.y), a3);
            a0 = fmaf(w1, bflo(r1.x), a0); a1 = fmaf(w1, bfhi(r1.x), a1);
            a2 = fmaf(w1, bflo(r1.y), a2); a3 = fmaf(w1, bfhi(r1.y), a3);
            a0 = fmaf(w2, bflo(r2.x), a0); a1 = fmaf(w2, bfhi(r2.x), a1);
            a2 = fmaf(w2, bflo(r2.y), a2); a3 = fmaf(w2, bfhi(r2.y), a3);
            a0 = fmaf(w3, bflo(r3.x), a0); a1 = fmaf(w3, bfhi(r3.x), a1);
            a2 = fmaf(w3, bflo(r3.y), a2); a3 = fmaf(w3, bfhi(r3.y), a3);
        }
        for (; j < m; j += 2) {          // tail: lanes >= m carry w = 0
            int   ss = __shfl(s, j + half);
            float wv = __shfl(w, j + half);
            uint2 r = rows[(size_t)ss * 32 + fl];
            a0 = fmaf(wv, bflo(r.x), a0); a1 = fmaf(wv, bfhi(r.x), a1);
            a2 = fmaf(wv, bflo(r.y), a2); a3 = fmaf(wv, bfhi(r.y), a3);
        }
    }
    a0 += __shfl_xor(a0, 32);
    a1 += __shfl_xor(a1, 32);
    a2 += __shfl_xor(a2, 32);
    a3 += __shfl_xor(a3, 32);
    if (half == 0) {
        a0 *= dv; a1 *= dv; a2 *= dv; a3 *= dv;
        if (out_bf) {
            a0 += bias[fl * 4 + 0]; a1 += bias[fl * 4 + 1];
            a2 += bias[fl * 4 + 2]; a3 += bias[fl * 4 + 3];
            a0 = fmaxf(a0, 0.f); a1 = fmaxf(a1, 0.f);
            a2 = fmaxf(a2, 0.f); a3 = fmaxf(a3, 0.f);
            uint2 pk;
            pk.x = (bf16rne(a1) << 16) | bf16rne(a0);
            pk.y = (bf16rne(a3) << 16) | bf16rne(a2);
            ((uint2*)out_bf)[(size_t)v * 32 + fl] = pk;
        } else {
            float4 o = make_float4(a0, a1, a2, a3);
            ((float4*)out_f32)[(size_t)v * 32 + fl] = o;
        }
    }
}

// ---- GEMM1: Hbf = bf16(X @ W)  (n x 128) @ (128 x 128), fp32 math ----
__global__ __launch_bounds__(256) void k_gemm1(
    const float* __restrict__ X, const float* __restrict__ W,
    unsigned* __restrict__ Hbf, int n)
{
    __shared__ float xT[128][68];
    int tid = threadIdx.x;
    int tx = tid & 31, ty = tid >> 5;
    int nbase = blockIdx.x * 64;
    #pragma unroll
    for (int r = 0; r < 8; ++r) {
        int nl = r * 8 + ty;
        int node = nbase + nl;
        int k4 = tx * 4;
        float4 v = make_float4(0.f, 0.f, 0.f, 0.f);
        if (node < n) v = *(const float4*)&X[(size_t)node * 128 + k4];
        xT[k4 + 0][nl] = v.x; xT[k4 + 1][nl] = v.y;
        xT[k4 + 2][nl] = v.z; xT[k4 + 3][nl] = v.w;
    }
    __syncthreads();

    float acc[8][4];
    #pragma unroll
    for (int i = 0; i < 8; ++i)
        #pragma unroll
        for (int c = 0; c < 4; ++c) acc[i][c] = 0.f;

    int j0 = tx * 4;
    int n0 = ty * 8;
    #pragma unroll 4
    for (int k = 0; k < 128; ++k) {
        float4 wv = *(const float4*)&W[k * 128 + j0];
        float4 xa = *(const float4*)&xT[k][n0];
        float4 xb = *(const float4*)&xT[k][n0 + 4];
        float xv[8] = {xa.x, xa.y, xa.z, xa.w, xb.x, xb.y, xb.z, xb.w};
        float wc[4] = {wv.x, wv.y, wv.z, wv.w};
        #pragma unroll
        for (int i = 0; i < 8; ++i)
            #pragma unroll
            for (int c = 0; c < 4; ++c)
                acc[i][c] = fmaf(xv[i], wc[c], acc[i][c]);
    }
    #pragma unroll
    for (int i = 0; i < 8; ++i) {
        int node = nbase + n0 + i;
        if (node < n) {
            uint2 pk;
            pk.x = (bf16rne(acc[i][1]) << 16) | bf16rne(acc[i][0]);
            pk.y = (bf16rne(acc[i][3]) << 16) | bf16rne(acc[i][2]);
            ((uint2*)Hbf)[(size_t)node * 32 + tx] = pk;
        }
    }
}

// ---- GEMM2: out = G @ [Wmu | Wls] + [bmu | bls], split-written to d_out ----
__global__ __launch_bounds__(256) void k_gemm2(
    const float* __restrict__ G,
    const float* __restrict__ Wmu, const float* __restrict__ Wls,
    const float* __restrict__ bmu, const float* __restrict__ bls,
    float* __restrict__ out, int n)
{
    __shared__ float xT[128][68];
    int tid = threadIdx.x;
    int tx = tid & 31, ty = tid >> 5;
    int nbase = blockIdx.x * 64;
    #pragma unroll
    for (int r = 0; r < 8; ++r) {
        int nl = r * 8 + ty;
        int node = nbase + nl;
        int k4 = tx * 4;
        float4 v = make_float4(0.f, 0.f, 0.f, 0.f);
        if (node < n) v = *(const float4*)&G[(size_t)node * 128 + k4];
        xT[k4 + 0][nl] = v.x; xT[k4 + 1][nl] = v.y;
        xT[k4 + 2][nl] = v.z; xT[k4 + 3][nl] = v.w;
    }
    __syncthreads();

    float acc[8][4];
    #pragma unroll
    for (int i = 0; i < 8; ++i)
        #pragma unroll
        for (int c = 0; c < 4; ++c) acc[i][c] = 0.f;

    const float* Wh = (tx < 16) ? Wmu : Wls;
    int jj = (tx & 15) * 4;
    int n0 = ty * 8;
    #pragma unroll 4
    for (int k = 0; k < 128; ++k) {
        float4 wv = *(const float4*)&Wh[k * 64 + jj];
        float4 xa = *(const float4*)&xT[k][n0];
        float4 xb = *(const float4*)&xT[k][n0 + 4];
        float xv[8] = {xa.x, xa.y, xa.z, xa.w, xb.x, xb.y, xb.z, xb.w};
        float wc[4] = {wv.x, wv.y, wv.z, wv.w};
        #pragma unroll
        for (int i = 0; i < 8; ++i)
            #pragma unroll
            for (int c = 0; c < 4; ++c)
                acc[i][c] = fmaf(xv[i], wc[c], acc[i][c]);
    }
    const float* bh = (tx < 16) ? bmu : bls;
    float4 bb = *(const float4*)&bh[jj];
    size_t halfoff = (tx < 16) ? (size_t)0 : (size_t)n * 64;
    #pragma unroll
    for (int i = 0; i < 8; ++i) {
        int node = nbase + n0 + i;
        if (node < n) {
            float4 o = make_float4(acc[i][0] + bb.x, acc[i][1] + bb.y,
                                   acc[i][2] + bb.z, acc[i][3] + bb.w);
            *(float4*)&out[halfoff + (size_t)node * 64 + jj] = o;
        }
    }
}

extern "C" void kernel_launch(void* const* d_in, const int* in_sizes, int n_in,
                              void* d_out, int out_size, void* d_ws, size_t ws_size,
                              hipStream_t stream) {
    const float* x   = (const float*)d_in[0];
    const int*   ei  = (const int*)d_in[1];
    const float* W1  = (const float*)d_in[3];
    const float* b1  = (const float*)d_in[4];
    const float* Wmu = (const float*)d_in[5];
    const float* bmu = (const float*)d_in[6];
    const float* Wls = (const float*)d_in[7];
    const float* bls = (const float*)d_in[8];
    float* out = (float*)d_out;

    int n = in_sizes[0] / 128;   // 100000
    int e = in_sizes[1] / 2;     // 1600000
    const int* erow = ei;        // sources
    const int* ecol = ei + e;    // targets
    int nbuck = (n + BW - 1) >> BW_SH;

    char* p = (char*)d_ws;
    auto alloc = [&](size_t bytes) -> char* {
        char* q = p; p += (bytes + 255) & ~(size_t)255; return q;
    };
    int*      cnt   = (int*)     alloc((size_t)n * 4);
    int*      offs  = (int*)     alloc((size_t)n * 4);
    int*      bsum  = (int*)     alloc(512);
    int*      bbase = (int*)     alloc(512);
    int*      gcur  = (int*)     alloc(NBUCK_MAX * 4);
    float*    dinv  = (float*)   alloc((size_t)n * 4);
    int*      esrc  = (int*)     alloc((size_t)e * 4);
    unsigned* hbf   = (unsigned*)alloc((size_t)n * 64 * 4);   // bf16 h  (25.6 MB)
    unsigned* h1bf  = (unsigned*)alloc((size_t)n * 64 * 4);   // bf16 h1 (25.6 MB)
    float*    g     = (float*)   alloc((size_t)n * 128 * 4);  // fp32 g  (51.2 MB)
    int*      pairs = (int*)g;   // pairs[] dead before prop2 writes g

    int nb = (n + 1023) / 1024;

    k_zero_int<<<(n + 255) / 256, 256, 0, stream>>>(cnt, n);
    k_count<<<(e + 255) / 256, 256, 0, stream>>>(ecol, e, cnt);
    k_bsum<<<nb, 256, 0, stream>>>(cnt, n, bsum);
    k_scan_bsum<<<1, 128, 0, stream>>>(bsum, nb, bbase);
    k_scan_local<<<nb, 256, 0, stream>>>(cnt, bbase, offs, dinv, gcur, n);
    k_bucket<<<(e + EPB - 1) / EPB, 256, 0, stream>>>(erow, ecol, e, gcur, pairs);
    k_fill2<<<nbuck, 256, 0, stream>>>(offs, pairs, esrc, n, e);

    k_gemm1<<<(n + 63) / 64, 256, 0, stream>>>(x, W1, hbf, n);
    k_prop_bf<<<(n + 3) / 4, 256, 0, stream>>>(hbf, dinv, offs, cnt, esrc,
                                               h1bf, nullptr, b1, n);
    k_prop_bf<<<(n + 3) / 4, 256, 0, stream>>>(h1bf, dinv, offs, cnt, esrc,
                                               nullptr, g, nullptr, n);
    k_gemm2<<<(n + 63) / 64, 256, 0, stream>>>(g, Wmu, Wls, bmu, bls, out, n);
}

// Round 4
// 376.018 us; speedup vs baseline: 1.7214x; 1.2147x over previous
//
#include <hip/hip_runtime.h>
#include <hip/hip_bf16.h>

// ---------------------------------------------------------------------------
// GCN encoder: h1 = relu(P (x W1) + b1); mu = P (h1 Wmu) + bmu; ls likewise.
// P = D^-1/2 (A + I) D^-1/2, in-degree D.
// R4: (a) CSR build reworked: bucket-level histogram (k_bcnt, 196 counters)
//     replaces the n-wide atomic k_count (R3: 66 us, 50 MB write churn);
//     per-target cnt/offs/dinv now derived in-LDS inside k_fill3.
//     (b) both GEMMs moved to bf16 MFMA 16x16x32 (R3 fp32 GEMM: 66 us,
//     6M LDS bank conflicts from the transpose write). Weights pre-transposed
//     to bf16 once (k_wprep) so B-frags are single b128 loads; g table bf16.
// ---------------------------------------------------------------------------

#define BW_SH   9                 // bucket width = 512 targets
#define BW      (1 << BW_SH)
#define NBUCK_MAX 256             // supports n <= 131072
#define EPB     12288             // edges per k_bucket block
#define FCAP    10240             // LDS staging capacity (mean bucket ~8.2K)

typedef __attribute__((ext_vector_type(8))) short bf16x8;
typedef __attribute__((ext_vector_type(4))) float f32x4;

__device__ __forceinline__ unsigned bf16rne(float f) {   // fp32 -> bf16 bits (RNE)
    unsigned u = __float_as_uint(f);
    return (u + 0x7fffu + ((u >> 16) & 1u)) >> 16;
}
__device__ __forceinline__ float bflo(unsigned u) { return __uint_as_float(u << 16); }
__device__ __forceinline__ float bfhi(unsigned u) { return __uint_as_float(u & 0xffff0000u); }

// ---- weight prep: W1t[c][k]=bf16(W1[k][c]); Wct[c][k]=bf16([Wmu|Wls][k][c]);
// bcat = [bmu|bls].  grid 256 x 128 threads, tiny one-shot.
__global__ void k_wprep(const float* __restrict__ W1,
                        const float* __restrict__ Wmu, const float* __restrict__ Wls,
                        const float* __restrict__ bmu, const float* __restrict__ bls,
                        unsigned short* __restrict__ W1t,
                        unsigned short* __restrict__ Wct,
                        float* __restrict__ bcat) {
    int b = blockIdx.x, t = threadIdx.x;    // t = k index
    if (b < 128) {
        W1t[b * 128 + t] = (unsigned short)bf16rne(W1[t * 128 + b]);
        if (b == 0) bcat[t] = (t < 64) ? bmu[t] : bls[t - 64];
    } else {
        int c = b - 128;
        float w = (c < 64) ? Wmu[t * 64 + c] : Wls[t * 64 + (c - 64)];
        Wct[c * 128 + t] = (unsigned short)bf16rne(w);
    }
}

// ---- bucket-level histogram: 196 counters, LDS-privatized ----
__global__ __launch_bounds__(256) void k_bcnt(const int* __restrict__ col, int e,
                                              int* __restrict__ bcnt) {
    __shared__ int h[NBUCK_MAX];
    int tid = threadIdx.x;
    for (int i = tid; i < NBUCK_MAX; i += 256) h[i] = 0;
    __syncthreads();
    int i0 = blockIdx.x * 8192;
    int i1 = min(e, i0 + 8192);
    for (int i = i0 + tid; i < i1; i += 256) atomicAdd(&h[col[i] >> BW_SH], 1);
    __syncthreads();
    for (int i = tid; i < NBUCK_MAX; i += 256)
        if (h[i]) atomicAdd(&bcnt[i], h[i]);
}

// ---- exclusive scan of bucket counts -> bbase (+sentinel), init gcur ----
__global__ void k_bscan(const int* __restrict__ bcnt, int* __restrict__ bbase,
                        int* __restrict__ gcur, int nbuck, int e) {
    __shared__ int sh[256];
    int t = threadIdx.x;
    int v = (t < nbuck) ? bcnt[t] : 0;
    sh[t] = v; __syncthreads();
    for (int d = 1; d < 256; d <<= 1) {
        int u = (t >= d) ? sh[t - d] : 0;
        __syncthreads();
        sh[t] += u;
        __syncthreads();
    }
    if (t < nbuck) { bbase[t] = sh[t] - v; gcur[t] = sh[t] - v; }
    if (t == 0) bbase[nbuck] = e;
}

// ---- pass 1: bucket edges by target/512 into bucket-contiguous pairs[] ----
__global__ __launch_bounds__(256) void k_bucket(
    const int* __restrict__ row, const int* __restrict__ col, int e,
    int* __restrict__ gcur, int* __restrict__ pairs)
{
    __shared__ int items[EPB];
    __shared__ unsigned char bkt[EPB];
    __shared__ int hcnt[NBUCK_MAX];
    __shared__ int lbase[NBUCK_MAX];
    int tid = threadIdx.x;
    int e0 = blockIdx.x * EPB;
    int e1 = min(e, e0 + EPB);
    int m = e1 - e0;
    for (int b = tid; b < NBUCK_MAX; b += 256) hcnt[b] = 0;
    __syncthreads();
    for (int i = tid; i < m; i += 256) {
        int s = row[e0 + i];
        int d = col[e0 + i];
        items[i] = (s << BW_SH) | (d & (BW - 1));
        int b = d >> BW_SH;
        bkt[i] = (unsigned char)b;
        atomicAdd(&hcnt[b], 1);
    }
    __syncthreads();
    for (int b = tid; b < NBUCK_MAX; b += 256)
        lbase[b] = hcnt[b] ? atomicAdd(&gcur[b], hcnt[b]) : 0;
    __syncthreads();
    for (int i = tid; i < m; i += 256) {
        int pos = atomicAdd(&lbase[bkt[i]], 1);
        pairs[pos] = items[i];
    }
}

// ---- pass 2: per-bucket hist + scan + scatter; emits cnt/offs/dinv/esrc ----
__global__ __launch_bounds__(256) void k_fill3(
    const int* __restrict__ bbase, const int* __restrict__ pairs,
    int* __restrict__ offs, int* __restrict__ cnt, float* __restrict__ dinv,
    int* __restrict__ esrc, int n)
{
    __shared__ int lcnt[BW];
    __shared__ int loffs[BW];
    __shared__ int lcur[BW];
    __shared__ int sscan[256];
    __shared__ int lesrc[FCAP];
    int b = blockIdx.x, tid = threadIdx.x;
    int t0 = b << BW_SH;
    int nt = min(n - t0, BW);
    int cbase = bbase[b], cend = bbase[b + 1];
    int m = cend - cbase;
    for (int i = tid; i < BW; i += 256) lcnt[i] = 0;
    __syncthreads();
    for (int i = tid; i < m; i += 256)
        atomicAdd(&lcnt[pairs[cbase + i] & (BW - 1)], 1);
    __syncthreads();
    int s = lcnt[2 * tid] + lcnt[2 * tid + 1];
    sscan[tid] = s; __syncthreads();
    for (int d = 1; d < 256; d <<= 1) {
        int u = (tid >= d) ? sscan[tid - d] : 0;
        __syncthreads();
        sscan[tid] += u;
        __syncthreads();
    }
    int ex = sscan[tid] - s;
    loffs[2 * tid] = ex;              lcur[2 * tid] = ex;
    loffs[2 * tid + 1] = ex + lcnt[2 * tid];
    lcur[2 * tid + 1] = ex + lcnt[2 * tid];
    __syncthreads();
    for (int t = tid; t < nt; t += 256) {
        int c = lcnt[t];
        offs[t0 + t] = cbase + loffs[t];
        cnt[t0 + t]  = c;
        dinv[t0 + t] = 1.0f / sqrtf((float)(c + 1));
    }
    if (m <= FCAP) {
        for (int i = tid; i < m; i += 256) {
            int it = pairs[cbase + i];
            int pos = atomicAdd(&lcur[it & (BW - 1)], 1);
            lesrc[pos] = it >> BW_SH;
        }
        __syncthreads();
        for (int i = tid; i < m; i += 256)
            esrc[cbase + i] = lesrc[i];
    } else {            // statistically unreachable fallback
        for (int i = tid; i < m; i += 256) {
            int it = pairs[cbase + i];
            int pos = atomicAdd(&lcur[it & (BW - 1)], 1);
            esrc[cbase + pos] = it >> BW_SH;
        }
    }
}

// ---- propagation over bf16 table: one wave per node, 2 edges in parallel ----
__global__ __launch_bounds__(256) void k_prop_bf(
    const unsigned* __restrict__ hbf, const float* __restrict__ dinv,
    const int* __restrict__ offs, const int* __restrict__ cnt,
    const int* __restrict__ esrc,
    unsigned* __restrict__ out_bf,
    const float* __restrict__ bias, int do_relu, int n)
{
    int wid  = (blockIdx.x * blockDim.x + threadIdx.x) >> 6;
    if (wid >= n) return;
    int lane = threadIdx.x & 63;
    int half = lane >> 5;
    int fl   = lane & 31;
    int v = wid;
    float dv = dinv[v];
    int start = offs[v];
    int deg   = cnt[v];
    const uint2* rows = (const uint2*)hbf;

    float a0 = 0.f, a1 = 0.f, a2 = 0.f, a3 = 0.f;
    if (half == 0) {
        uint2 r = rows[(size_t)v * 32 + fl];
        a0 = dv * bflo(r.x); a1 = dv * bfhi(r.x);
        a2 = dv * bflo(r.y); a3 = dv * bfhi(r.y);
    }
    for (int base = 0; base < deg; base += 64) {
        int m = min(64, deg - base);
        int s = 0; float w = 0.f;
        if (lane < m) { s = esrc[start + base + lane]; w = dinv[s]; }
        int j = 0;
        for (; j + 8 <= m; j += 8) {
            int   s0 = __shfl(s, j + 0 + half), s1 = __shfl(s, j + 2 + half);
            int   s2 = __shfl(s, j + 4 + half), s3 = __shfl(s, j + 6 + half);
            float w0 = __shfl(w, j + 0 + half), w1 = __shfl(w, j + 2 + half);
            float w2 = __shfl(w, j + 4 + half), w3 = __shfl(w, j + 6 + half);
            uint2 r0 = rows[(size_t)s0 * 32 + fl];
            uint2 r1 = rows[(size_t)s1 * 32 + fl];
            uint2 r2 = rows[(size_t)s2 * 32 + fl];
            uint2 r3 = rows[(size_t)s3 * 32 + fl];
            a0 = fmaf(w0, bflo(r0.x), a0); a1 = fmaf(w0, bfhi(r0.x), a1);
            a2 = fmaf(w0, bflo(r0.y), a2); a3 = fmaf(w0, bfhi(r0.y), a3);
            a0 = fmaf(w1, bflo(r1.x), a0); a1 = fmaf(w1, bfhi(r1.x), a1);
            a2 = fmaf(w1, bflo(r1.y), a2); a3 = fmaf(w1, bfhi(r1.y), a3);
            a0 = fmaf(w2, bflo(r2.x), a0); a1 = fmaf(w2, bfhi(r2.x), a1);
            a2 = fmaf(w2, bflo(r2.y), a2); a3 = fmaf(w2, bfhi(r2.y), a3);
            a0 = fmaf(w3, bflo(r3.x), a0); a1 = fmaf(w3, bfhi(r3.x), a1);
            a2 = fmaf(w3, bflo(r3.y), a2); a3 = fmaf(w3, bfhi(r3.y), a3);
        }
        for (; j < m; j += 2) {
            int   ss = __shfl(s, j + half);
            float wv = __shfl(w, j + half);
            uint2 r = rows[(size_t)ss * 32 + fl];
            a0 = fmaf(wv, bflo(r.x), a0); a1 = fmaf(wv, bfhi(r.x), a1);
            a2 = fmaf(wv, bflo(r.y), a2); a3 = fmaf(wv, bfhi(r.y), a3);
        }
    }
    a0 += __shfl_xor(a0, 32);
    a1 += __shfl_xor(a1, 32);
    a2 += __shfl_xor(a2, 32);
    a3 += __shfl_xor(a3, 32);
    if (half == 0) {
        a0 *= dv; a1 *= dv; a2 *= dv; a3 *= dv;
        if (bias) {
            a0 += bias[fl * 4 + 0]; a1 += bias[fl * 4 + 1];
            a2 += bias[fl * 4 + 2]; a3 += bias[fl * 4 + 3];
        }
        if (do_relu) {
            a0 = fmaxf(a0, 0.f); a1 = fmaxf(a1, 0.f);
            a2 = fmaxf(a2, 0.f); a3 = fmaxf(a3, 0.f);
        }
        uint2 pk;
        pk.x = (bf16rne(a1) << 16) | bf16rne(a0);
        pk.y = (bf16rne(a3) << 16) | bf16rne(a2);
        ((uint2*)out_bf)[(size_t)v * 32 + fl] = pk;
    }
}

// ---- GEMM1 (MFMA): Hbf = bf16( X @ W1 ), per wave 16 nodes x 128 cols ----
// A[m=node][k] from X rows (fp32->bf16); B[k][n=col] from W1t[c][k] (b128).
// D layout: lane holds D[row=q*4+r][col=cb*16+(lane&15)] (m89/m91 mapping).
__global__ __launch_bounds__(256) void k_gemm1(
    const float* __restrict__ X, const unsigned short* __restrict__ W1t,
    unsigned* __restrict__ Hbf, int n)
{
    __shared__ unsigned short ot[4][16][136];
    int tid = threadIdx.x;
    int w = tid >> 6, L = tid & 63;
    int q = L >> 4, ml = L & 15;
    int nb0 = blockIdx.x * 64 + w * 16;
    int node = nb0 + ml;
    bool valid = node < n;
    const bf16x8* Bp = (const bf16x8*)W1t;
    f32x4 acc[8];
    #pragma unroll
    for (int cb = 0; cb < 8; ++cb) { acc[cb][0]=0.f; acc[cb][1]=0.f; acc[cb][2]=0.f; acc[cb][3]=0.f; }
    #pragma unroll
    for (int kc = 0; kc < 4; ++kc) {
        bf16x8 af = {0,0,0,0,0,0,0,0};
        if (valid) {
            const float4* xp = (const float4*)&X[(size_t)node * 128 + kc * 32 + q * 8];
            float4 xa = xp[0], xb = xp[1];
            af[0] = (short)bf16rne(xa.x); af[1] = (short)bf16rne(xa.y);
            af[2] = (short)bf16rne(xa.z); af[3] = (short)bf16rne(xa.w);
            af[4] = (short)bf16rne(xb.x); af[5] = (short)bf16rne(xb.y);
            af[6] = (short)bf16rne(xb.z); af[7] = (short)bf16rne(xb.w);
        }
        #pragma unroll
        for (int cb = 0; cb < 8; ++cb) {
            bf16x8 bfr = Bp[(cb * 16 + ml) * 16 + kc * 4 + q];
            acc[cb] = __builtin_amdgcn_mfma_f32_16x16x32_bf16(af, bfr, acc[cb], 0, 0, 0);
        }
    }
    #pragma unroll
    for (int cb = 0; cb < 8; ++cb)
        #pragma unroll
        for (int r = 0; r < 4; ++r)
            ot[w][q * 4 + r][cb * 16 + ml] = (unsigned short)bf16rne(acc[cb][r]);
    __syncthreads();
    #pragma unroll
    for (int it = 0; it < 4; ++it) {
        int flat = it * 64 + L;
        int row = flat >> 4, cg = flat & 15;
        int nd = nb0 + row;
        if (nd < n) {
            uint4 v = *(const uint4*)&ot[w][row][cg * 8];
            *(uint4*)&Hbf[(size_t)nd * 64 + cg * 4] = v;
        }
    }
}

// ---- GEMM2 (MFMA): out = G @ [Wmu|Wls] + [bmu|bls], split fp32 write ----
__global__ __launch_bounds__(256) void k_gemm2(
    const unsigned* __restrict__ Gbf, const unsigned short* __restrict__ Wct,
    const float* __restrict__ bcat, float* __restrict__ out, int n)
{
    __shared__ float ot[4][16][132];
    int tid = threadIdx.x;
    int w = tid >> 6, L = tid & 63;
    int q = L >> 4, ml = L & 15;
    int nb0 = blockIdx.x * 64 + w * 16;
    int node = nb0 + ml;
    bool valid = node < n;
    const bf16x8* Ap = (const bf16x8*)Gbf;
    const bf16x8* Bp = (const bf16x8*)Wct;
    f32x4 acc[8];
    #pragma unroll
    for (int cb = 0; cb < 8; ++cb) { acc[cb][0]=0.f; acc[cb][1]=0.f; acc[cb][2]=0.f; acc[cb][3]=0.f; }
    #pragma unroll
    for (int kc = 0; kc < 4; ++kc) {
        bf16x8 af = {0,0,0,0,0,0,0,0};
        if (valid) af = Ap[(size_t)node * 16 + kc * 4 + q];
        #pragma unroll
        for (int cb = 0; cb < 8; ++cb) {
            bf16x8 bfr = Bp[(cb * 16 + ml) * 16 + kc * 4 + q];
            acc[cb] = __builtin_amdgcn_mfma_f32_16x16x32_bf16(af, bfr, acc[cb], 0, 0, 0);
        }
    }
    #pragma unroll
    for (int cb = 0; cb < 8; ++cb)
        #pragma unroll
        for (int r = 0; r < 4; ++r)
            ot[w][q * 4 + r][cb * 16 + ml] = acc[cb][r];
    __syncthreads();
    #pragma unroll
    for (int it = 0; it < 8; ++it) {
        int flat = it * 64 + L;
        int row = flat >> 5, c4 = flat & 31;
        int col = c4 * 4;
        int nd = nb0 + row;
        if (nd < n) {
            float4 v = *(const float4*)&ot[w][row][col];
            float4 bb = *(const float4*)&bcat[col];
            v.x += bb.x; v.y += bb.y; v.z += bb.z; v.w += bb.w;
            size_t off = (col < 64)
                ? ((size_t)nd * 64 + col)
                : ((size_t)n * 64 + (size_t)nd * 64 + (col - 64));
            *(float4*)&out[off] = v;
        }
    }
}

extern "C" void kernel_launch(void* const* d_in, const int* in_sizes, int n_in,
                              void* d_out, int out_size, void* d_ws, size_t ws_size,
                              hipStream_t stream) {
    const float* x   = (const float*)d_in[0];
    const int*   ei  = (const int*)d_in[1];
    const float* W1  = (const float*)d_in[3];
    const float* b1  = (const float*)d_in[4];
    const float* Wmu = (const float*)d_in[5];
    const float* bmu = (const float*)d_in[6];
    const float* Wls = (const float*)d_in[7];
    const float* bls = (const float*)d_in[8];
    float* out = (float*)d_out;

    int n = in_sizes[0] / 128;   // 100000
    int e = in_sizes[1] / 2;     // 1600000
    const int* erow = ei;        // sources
    const int* ecol = ei + e;    // targets
    int nbuck = (n + BW - 1) >> BW_SH;   // 196

    char* p = (char*)d_ws;
    auto alloc = [&](size_t bytes) -> char* {
        char* q = p; p += (bytes + 255) & ~(size_t)255; return q;
    };
    int*            bcnt  = (int*)           alloc((NBUCK_MAX + 1) * 4);
    int*            bbase = (int*)           alloc((NBUCK_MAX + 1) * 4);
    int*            gcur  = (int*)           alloc(NBUCK_MAX * 4);
    int*            cnt   = (int*)           alloc((size_t)n * 4);
    int*            offs  = (int*)           alloc((size_t)n * 4);
    float*          dinv  = (float*)         alloc((size_t)n * 4);
    int*            esrc  = (int*)           alloc((size_t)e * 4);
    unsigned short* W1t   = (unsigned short*)alloc(128 * 128 * 2);
    unsigned short* Wct   = (unsigned short*)alloc(128 * 128 * 2);
    float*          bcat  = (float*)         alloc(128 * 4);
    unsigned*       hbf   = (unsigned*)      alloc((size_t)n * 64 * 4);
    unsigned*       h1bf  = (unsigned*)      alloc((size_t)n * 64 * 4);
    unsigned*       gbf   = (unsigned*)      alloc((size_t)n * 64 * 4);
    int*            pairs = (int*)gbf;   // dead before prop2 writes gbf

    hipMemsetAsync(bcnt, 0, (NBUCK_MAX + 1) * 4, stream);
    k_wprep<<<256, 128, 0, stream>>>(W1, Wmu, Wls, bmu, bls, W1t, Wct, bcat);
    k_bcnt<<<(e + 8191) / 8192, 256, 0, stream>>>(ecol, e, bcnt);
    k_bscan<<<1, 256, 0, stream>>>(bcnt, bbase, gcur, nbuck, e);
    k_bucket<<<(e + EPB - 1) / EPB, 256, 0, stream>>>(erow, ecol, e, gcur, pairs);
    k_fill3<<<nbuck, 256, 0, stream>>>(bbase, pairs, offs, cnt, dinv, esrc, n);

    k_gemm1<<<(n + 63) / 64, 256, 0, stream>>>(x, W1t, hbf, n);
    k_prop_bf<<<(n + 3) / 4, 256, 0, stream>>>(hbf, dinv, offs, cnt, esrc,
                                               h1bf, b1, 1, n);
    k_prop_bf<<<(n + 3) / 4, 256, 0, stream>>>(h1bf, dinv, offs, cnt, esrc,
                                               gbf, nullptr, 0, n);
    k_gemm2<<<(n + 63) / 64, 256, 0, stream>>>(gbf, Wct, bcat, out, n);
}

// Round 5
// 346.256 us; speedup vs baseline: 1.8694x; 1.0860x over previous
//
#include <hip/hip_runtime.h>
#include <hip/hip_bf16.h>

// ---------------------------------------------------------------------------
// GCN encoder: h1 = relu(P (x W1) + b1); mu = P (h1 Wmu) + bmu; ls likewise.
// P = D^-1/2 (A + I) D^-1/2, in-degree D.
// R5: (a) padded-bucket CSR: each 512-target bucket owns a fixed CAP-slot
//     segment of pairs[]/esrc[]; offs[] points into the padded layout, so
//     the exact-prefix scan chain (k_bcnt/k_bscan/memset) is deleted and
//     k_bucket gets 2x more blocks (EPB 6144).
//     (b) k_prop gather loop unrolled to 16 edges / 8 loads in flight
//     (R4: latency-bound at 43% VALUBusy, 4 loads in flight, VGPR=24).
// ---------------------------------------------------------------------------

#define BW_SH   9                 // bucket width = 512 targets
#define BW      (1 << BW_SH)
#define NBUCK_MAX 256             // supports n <= 131072
#define EPB     6144              // edges per k_bucket block -> 261 blocks
#define CAP     10240             // per-bucket segment slots (mean 8192, sd 90)

typedef __attribute__((ext_vector_type(8))) short bf16x8;
typedef __attribute__((ext_vector_type(4))) float f32x4;

__device__ __forceinline__ unsigned bf16rne(float f) {   // fp32 -> bf16 bits (RNE)
    unsigned u = __float_as_uint(f);
    return (u + 0x7fffu + ((u >> 16) & 1u)) >> 16;
}
__device__ __forceinline__ float bflo(unsigned u) { return __uint_as_float(u << 16); }
__device__ __forceinline__ float bfhi(unsigned u) { return __uint_as_float(u & 0xffff0000u); }

// ---- init per-bucket cursors to segment bases ----
__global__ void k_init(int* __restrict__ gcur, int nbuck) {
    int t = threadIdx.x;
    for (int b = t; b < nbuck; b += 256) gcur[b] = b * CAP;
}

// ---- weight prep: W1t[c][k]=bf16(W1[k][c]); Wct[c][k]=bf16([Wmu|Wls][k][c]) ----
__global__ void k_wprep(const float* __restrict__ W1,
                        const float* __restrict__ Wmu, const float* __restrict__ Wls,
                        const float* __restrict__ bmu, const float* __restrict__ bls,
                        unsigned short* __restrict__ W1t,
                        unsigned short* __restrict__ Wct,
                        float* __restrict__ bcat) {
    int b = blockIdx.x, t = threadIdx.x;    // t = k index
    if (b < 128) {
        W1t[b * 128 + t] = (unsigned short)bf16rne(W1[t * 128 + b]);
        if (b == 0) bcat[t] = (t < 64) ? bmu[t] : bls[t - 64];
    } else {
        int c = b - 128;
        float w = (c < 64) ? Wmu[t * 64 + c] : Wls[t * 64 + (c - 64)];
        Wct[c * 128 + t] = (unsigned short)bf16rne(w);
    }
}

// ---- pass 1: bucket edges by target/512 into padded per-bucket segments ----
__global__ __launch_bounds__(256) void k_bucket(
    const int* __restrict__ row, const int* __restrict__ col, int e,
    int* __restrict__ gcur, int* __restrict__ pairs)
{
    __shared__ int items[EPB];
    __shared__ unsigned char bkt[EPB];
    __shared__ int hcnt[NBUCK_MAX];
    __shared__ int lbase[NBUCK_MAX];
    int tid = threadIdx.x;
    int e0 = blockIdx.x * EPB;
    int e1 = min(e, e0 + EPB);
    int m = e1 - e0;
    for (int b = tid; b < NBUCK_MAX; b += 256) hcnt[b] = 0;
    __syncthreads();
    for (int i = tid; i < m; i += 256) {
        int s = row[e0 + i];
        int d = col[e0 + i];
        items[i] = (s << BW_SH) | (d & (BW - 1));
        int b = d >> BW_SH;
        bkt[i] = (unsigned char)b;
        atomicAdd(&hcnt[b], 1);
    }
    __syncthreads();
    for (int b = tid; b < NBUCK_MAX; b += 256)
        lbase[b] = hcnt[b] ? atomicAdd(&gcur[b], hcnt[b]) : 0;
    __syncthreads();
    for (int i = tid; i < m; i += 256) {
        int pos = atomicAdd(&lbase[bkt[i]], 1);
        pairs[pos] = items[i];
    }
}

// ---- pass 2: per-bucket hist + scan + LDS scatter; emits cnt/offs/dinv/esrc
// (esrc lives in the padded layout; offs[] points into it) ----
__global__ __launch_bounds__(256) void k_fill4(
    const int* __restrict__ gcur, const int* __restrict__ pairs,
    int* __restrict__ offs, int* __restrict__ cnt, float* __restrict__ dinv,
    int* __restrict__ esrc, int n)
{
    __shared__ int lcnt[BW];
    __shared__ int loffs[BW];
    __shared__ int lcur[BW];
    __shared__ int sscan[256];
    __shared__ int lesrc[CAP];
    int b = blockIdx.x, tid = threadIdx.x;
    int t0 = b << BW_SH;
    int nt = min(n - t0, BW);
    int base = b * CAP;
    int m = min(gcur[b] - base, CAP);
    for (int i = tid; i < BW; i += 256) lcnt[i] = 0;
    __syncthreads();
    for (int i = tid; i < m; i += 256)
        atomicAdd(&lcnt[pairs[base + i] & (BW - 1)], 1);
    __syncthreads();
    int s = lcnt[2 * tid] + lcnt[2 * tid + 1];
    sscan[tid] = s; __syncthreads();
    for (int d = 1; d < 256; d <<= 1) {
        int u = (tid >= d) ? sscan[tid - d] : 0;
        __syncthreads();
        sscan[tid] += u;
        __syncthreads();
    }
    int ex = sscan[tid] - s;
    loffs[2 * tid] = ex;              lcur[2 * tid] = ex;
    loffs[2 * tid + 1] = ex + lcnt[2 * tid];
    lcur[2 * tid + 1] = ex + lcnt[2 * tid];
    __syncthreads();
    for (int t = tid; t < nt; t += 256) {
        int c = lcnt[t];
        offs[t0 + t] = base + loffs[t];
        cnt[t0 + t]  = c;
        dinv[t0 + t] = 1.0f / sqrtf((float)(c + 1));
    }
    for (int i = tid; i < m; i += 256) {
        int it = pairs[base + i];
        int pos = atomicAdd(&lcur[it & (BW - 1)], 1);
        lesrc[pos] = it >> BW_SH;
    }
    __syncthreads();
    for (int i = tid; i < m; i += 256)
        esrc[base + i] = lesrc[i];
}

// ---- propagation over bf16 table: one wave per node, 2 edges in parallel,
// 16-edge unroll = 8 independent uint2 gathers in flight ----
__global__ __launch_bounds__(256) void k_prop_bf(
    const unsigned* __restrict__ hbf, const float* __restrict__ dinv,
    const int* __restrict__ offs, const int* __restrict__ cnt,
    const int* __restrict__ esrc,
    unsigned* __restrict__ out_bf,
    const float* __restrict__ bias, int do_relu, int n)
{
    int wid  = (blockIdx.x * blockDim.x + threadIdx.x) >> 6;
    if (wid >= n) return;
    int lane = threadIdx.x & 63;
    int half = lane >> 5;
    int fl   = lane & 31;
    int v = wid;
    float dv = dinv[v];
    int start = offs[v];
    int deg   = cnt[v];
    const uint2* rows = (const uint2*)hbf;

    float a0 = 0.f, a1 = 0.f, a2 = 0.f, a3 = 0.f;
    if (half == 0) {
        uint2 r = rows[(size_t)v * 32 + fl];
        a0 = dv * bflo(r.x); a1 = dv * bfhi(r.x);
        a2 = dv * bflo(r.y); a3 = dv * bfhi(r.y);
    }
    for (int base = 0; base < deg; base += 64) {
        int m = min(64, deg - base);
        int s = 0; float w = 0.f;
        if (lane < m) { s = esrc[start + base + lane]; w = dinv[s]; }
        int j = 0;
        for (; j + 16 <= m; j += 16) {   // 8 row-loads in flight per wave
            int si[8]; float wi[8]; uint2 r[8];
            #pragma unroll
            for (int u = 0; u < 8; ++u) {
                si[u] = __shfl(s, j + 2 * u + half);
                wi[u] = __shfl(w, j + 2 * u + half);
            }
            #pragma unroll
            for (int u = 0; u < 8; ++u) r[u] = rows[(size_t)si[u] * 32 + fl];
            #pragma unroll
            for (int u = 0; u < 8; ++u) {
                a0 = fmaf(wi[u], bflo(r[u].x), a0);
                a1 = fmaf(wi[u], bfhi(r[u].x), a1);
                a2 = fmaf(wi[u], bflo(r[u].y), a2);
                a3 = fmaf(wi[u], bfhi(r[u].y), a3);
            }
        }
        for (; j + 8 <= m; j += 8) {
            int si[4]; float wi[4]; uint2 r[4];
            #pragma unroll
            for (int u = 0; u < 4; ++u) {
                si[u] = __shfl(s, j + 2 * u + half);
                wi[u] = __shfl(w, j + 2 * u + half);
            }
            #pragma unroll
            for (int u = 0; u < 4; ++u) r[u] = rows[(size_t)si[u] * 32 + fl];
            #pragma unroll
            for (int u = 0; u < 4; ++u) {
                a0 = fmaf(wi[u], bflo(r[u].x), a0);
                a1 = fmaf(wi[u], bfhi(r[u].x), a1);
                a2 = fmaf(wi[u], bflo(r[u].y), a2);
                a3 = fmaf(wi[u], bfhi(r[u].y), a3);
            }
        }
        for (; j < m; j += 2) {          // tail: lanes >= m carry w = 0
            int   ss = __shfl(s, j + half);
            float wv = __shfl(w, j + half);
            uint2 r = rows[(size_t)ss * 32 + fl];
            a0 = fmaf(wv, bflo(r.x), a0); a1 = fmaf(wv, bfhi(r.x), a1);
            a2 = fmaf(wv, bflo(r.y), a2); a3 = fmaf(wv, bfhi(r.y), a3);
        }
    }
    a0 += __shfl_xor(a0, 32);
    a1 += __shfl_xor(a1, 32);
    a2 += __shfl_xor(a2, 32);
    a3 += __shfl_xor(a3, 32);
    if (half == 0) {
        a0 *= dv; a1 *= dv; a2 *= dv; a3 *= dv;
        if (bias) {
            a0 += bias[fl * 4 + 0]; a1 += bias[fl * 4 + 1];
            a2 += bias[fl * 4 + 2]; a3 += bias[fl * 4 + 3];
        }
        if (do_relu) {
            a0 = fmaxf(a0, 0.f); a1 = fmaxf(a1, 0.f);
            a2 = fmaxf(a2, 0.f); a3 = fmaxf(a3, 0.f);
        }
        uint2 pk;
        pk.x = (bf16rne(a1) << 16) | bf16rne(a0);
        pk.y = (bf16rne(a3) << 16) | bf16rne(a2);
        ((uint2*)out_bf)[(size_t)v * 32 + fl] = pk;
    }
}

// ---- GEMM1 (MFMA): Hbf = bf16( X @ W1 ), per wave 16 nodes x 128 cols ----
__global__ __launch_bounds__(256) void k_gemm1(
    const float* __restrict__ X, const unsigned short* __restrict__ W1t,
    unsigned* __restrict__ Hbf, int n)
{
    __shared__ unsigned short ot[4][16][136];
    int tid = threadIdx.x;
    int w = tid >> 6, L = tid & 63;
    int q = L >> 4, ml = L & 15;
    int nb0 = blockIdx.x * 64 + w * 16;
    int node = nb0 + ml;
    bool valid = node < n;
    const bf16x8* Bp = (const bf16x8*)W1t;
    f32x4 acc[8];
    #pragma unroll
    for (int cb = 0; cb < 8; ++cb) { acc[cb][0]=0.f; acc[cb][1]=0.f; acc[cb][2]=0.f; acc[cb][3]=0.f; }
    #pragma unroll
    for (int kc = 0; kc < 4; ++kc) {
        bf16x8 af = {0,0,0,0,0,0,0,0};
        if (valid) {
            const float4* xp = (const float4*)&X[(size_t)node * 128 + kc * 32 + q * 8];
            float4 xa = xp[0], xb = xp[1];
            af[0] = (short)bf16rne(xa.x); af[1] = (short)bf16rne(xa.y);
            af[2] = (short)bf16rne(xa.z); af[3] = (short)bf16rne(xa.w);
            af[4] = (short)bf16rne(xb.x); af[5] = (short)bf16rne(xb.y);
            af[6] = (short)bf16rne(xb.z); af[7] = (short)bf16rne(xb.w);
        }
        #pragma unroll
        for (int cb = 0; cb < 8; ++cb) {
            bf16x8 bfr = Bp[(cb * 16 + ml) * 16 + kc * 4 + q];
            acc[cb] = __builtin_amdgcn_mfma_f32_16x16x32_bf16(af, bfr, acc[cb], 0, 0, 0);
        }
    }
    #pragma unroll
    for (int cb = 0; cb < 8; ++cb)
        #pragma unroll
        for (int r = 0; r < 4; ++r)
            ot[w][q * 4 + r][cb * 16 + ml] = (unsigned short)bf16rne(acc[cb][r]);
    __syncthreads();
    #pragma unroll
    for (int it = 0; it < 4; ++it) {
        int flat = it * 64 + L;
        int row = flat >> 4, cg = flat & 15;
        int nd = nb0 + row;
        if (nd < n) {
            uint4 v = *(const uint4*)&ot[w][row][cg * 8];
            *(uint4*)&Hbf[(size_t)nd * 64 + cg * 4] = v;
        }
    }
}

// ---- GEMM2 (MFMA): out = G @ [Wmu|Wls] + [bmu|bls], split fp32 write ----
__global__ __launch_bounds__(256) void k_gemm2(
    const unsigned* __restrict__ Gbf, const unsigned short* __restrict__ Wct,
    const float* __restrict__ bcat, float* __restrict__ out, int n)
{
    __shared__ float ot[4][16][132];
    int tid = threadIdx.x;
    int w = tid >> 6, L = tid & 63;
    int q = L >> 4, ml = L & 15;
    int nb0 = blockIdx.x * 64 + w * 16;
    int node = nb0 + ml;
    bool valid = node < n;
    const bf16x8* Ap = (const bf16x8*)Gbf;
    const bf16x8* Bp = (const bf16x8*)Wct;
    f32x4 acc[8];
    #pragma unroll
    for (int cb = 0; cb < 8; ++cb) { acc[cb][0]=0.f; acc[cb][1]=0.f; acc[cb][2]=0.f; acc[cb][3]=0.f; }
    #pragma unroll
    for (int kc = 0; kc < 4; ++kc) {
        bf16x8 af = {0,0,0,0,0,0,0,0};
        if (valid) af = Ap[(size_t)node * 16 + kc * 4 + q];
        #pragma unroll
        for (int cb = 0; cb < 8; ++cb) {
            bf16x8 bfr = Bp[(cb * 16 + ml) * 16 + kc * 4 + q];
            acc[cb] = __builtin_amdgcn_mfma_f32_16x16x32_bf16(af, bfr, acc[cb], 0, 0, 0);
        }
    }
    #pragma unroll
    for (int cb = 0; cb < 8; ++cb)
        #pragma unroll
        for (int r = 0; r < 4; ++r)
            ot[w][q * 4 + r][cb * 16 + ml] = acc[cb][r];
    __syncthreads();
    #pragma unroll
    for (int it = 0; it < 8; ++it) {
        int flat = it * 64 + L;
        int row = flat >> 5, c4 = flat & 31;
        int col = c4 * 4;
        int nd = nb0 + row;
        if (nd < n) {
            float4 v = *(const float4*)&ot[w][row][col];
            float4 bb = *(const float4*)&bcat[col];
            v.x += bb.x; v.y += bb.y; v.z += bb.z; v.w += bb.w;
            size_t off = (col < 64)
                ? ((size_t)nd * 64 + col)
                : ((size_t)n * 64 + (size_t)nd * 64 + (col - 64));
            *(float4*)&out[off] = v;
        }
    }
}

extern "C" void kernel_launch(void* const* d_in, const int* in_sizes, int n_in,
                              void* d_out, int out_size, void* d_ws, size_t ws_size,
                              hipStream_t stream) {
    const float* x   = (const float*)d_in[0];
    const int*   ei  = (const int*)d_in[1];
    const float* W1  = (const float*)d_in[3];
    const float* b1  = (const float*)d_in[4];
    const float* Wmu = (const float*)d_in[5];
    const float* bmu = (const float*)d_in[6];
    const float* Wls = (const float*)d_in[7];
    const float* bls = (const float*)d_in[8];
    float* out = (float*)d_out;

    int n = in_sizes[0] / 128;   // 100000
    int e = in_sizes[1] / 2;     // 1600000
    const int* erow = ei;        // sources
    const int* ecol = ei + e;    // targets
    int nbuck = (n + BW - 1) >> BW_SH;   // 196

    char* p = (char*)d_ws;
    auto alloc = [&](size_t bytes) -> char* {
        char* q = p; p += (bytes + 255) & ~(size_t)255; return q;
    };
    int*            gcur  = (int*)           alloc(NBUCK_MAX * 4);
    int*            cnt   = (int*)           alloc((size_t)n * 4);
    int*            offs  = (int*)           alloc((size_t)n * 4);
    float*          dinv  = (float*)         alloc((size_t)n * 4);
    int*            esrc  = (int*)           alloc((size_t)nbuck * CAP * 4);
    unsigned short* W1t   = (unsigned short*)alloc(128 * 128 * 2);
    unsigned short* Wct   = (unsigned short*)alloc(128 * 128 * 2);
    float*          bcat  = (float*)         alloc(128 * 4);
    unsigned*       hbf   = (unsigned*)      alloc((size_t)n * 64 * 4);
    unsigned*       h1bf  = (unsigned*)      alloc((size_t)n * 64 * 4);
    unsigned*       gbf   = (unsigned*)      alloc((size_t)n * 64 * 4);
    int*            pairs = (int*)gbf;   // dead before prop2 writes gbf

    k_init<<<1, 256, 0, stream>>>(gcur, nbuck);
    k_wprep<<<256, 128, 0, stream>>>(W1, Wmu, Wls, bmu, bls, W1t, Wct, bcat);
    k_bucket<<<(e + EPB - 1) / EPB, 256, 0, stream>>>(erow, ecol, e, gcur, pairs);
    k_fill4<<<nbuck, 256, 0, stream>>>(gcur, pairs, offs, cnt, dinv, esrc, n);

    k_gemm1<<<(n + 63) / 64, 256, 0, stream>>>(x, W1t, hbf, n);
    k_prop_bf<<<(n + 3) / 4, 256, 0, stream>>>(hbf, dinv, offs, cnt, esrc,
                                               h1bf, b1, 1, n);
    k_prop_bf<<<(n + 3) / 4, 256, 0, stream>>>(h1bf, dinv, offs, cnt, esrc,
                                               gbf, nullptr, 0, n);
    k_gemm2<<<(n + 63) / 64, 256, 0, stream>>>(gbf, Wct, bcat, out, n);
}

// Round 6
// 320.265 us; speedup vs baseline: 2.0211x; 1.0812x over previous
//
#include <hip/hip_runtime.h>
#include <hip/hip_bf16.h>

// ---------------------------------------------------------------------------
// GCN encoder: h1 = relu(P (x W1) + b1); mu = P (h1 Wmu) + bmu; ls likewise.
// P = D^-1/2 (A + I) D^-1/2, in-degree D.
// R6: (a) k_bucket fused with k_gemm1 (independent work, one dispatch,
//     dynamic LDS) so the CSR bucket pass hides under the MFMA GEMM;
//     (b) buckets narrowed to 256 targets (391 blocks) -> k_fill 2x more
//     parallel, 6 blocks/CU; (c) gcur counters padded to 64B lines (cross-XCD
//     same-line atomic serialization); (d) k_init folded into k_wprep.
//     Props untouched: R5 showed they sit at the random-gather fabric
//     roofline (~3 TB/s L2-miss, MLP-insensitive).
// ---------------------------------------------------------------------------

#define BW_SH   8                 // bucket width = 256 targets
#define BW      (1 << BW_SH)
#define NBUCK_MAX 512             // supports n <= 131072
#define EPB     6144              // edges per bucket-pass block
#define CAP     5120              // per-bucket segment slots (mean 4092, sd 64)
#define GPAD    16                // gcur stride in ints (64B line per counter)

typedef __attribute__((ext_vector_type(8))) short bf16x8;
typedef __attribute__((ext_vector_type(4))) float f32x4;

__device__ __forceinline__ unsigned bf16rne(float f) {   // fp32 -> bf16 bits (RNE)
    unsigned u = __float_as_uint(f);
    return (u + 0x7fffu + ((u >> 16) & 1u)) >> 16;
}
__device__ __forceinline__ float bflo(unsigned u) { return __uint_as_float(u << 16); }
__device__ __forceinline__ float bfhi(unsigned u) { return __uint_as_float(u & 0xffff0000u); }

// ---- weight prep + gcur init: blocks 0..127 W1t, 128..255 Wct, 256..259 gcur
__global__ void k_wprep(const float* __restrict__ W1,
                        const float* __restrict__ Wmu, const float* __restrict__ Wls,
                        const float* __restrict__ bmu, const float* __restrict__ bls,
                        unsigned short* __restrict__ W1t,
                        unsigned short* __restrict__ Wct,
                        float* __restrict__ bcat,
                        int* __restrict__ gcur, int nbuck) {
    int b = blockIdx.x, t = threadIdx.x;    // t = k index
    if (b < 128) {
        W1t[b * 128 + t] = (unsigned short)bf16rne(W1[t * 128 + b]);
        if (b == 0) bcat[t] = (t < 64) ? bmu[t] : bls[t - 64];
    } else if (b < 256) {
        int c = b - 128;
        float w = (c < 64) ? Wmu[t * 64 + c] : Wls[t * 64 + (c - 64)];
        Wct[c * 128 + t] = (unsigned short)bf16rne(w);
    } else {
        int idx = (b - 256) * 128 + t;
        if (idx < nbuck) gcur[idx * GPAD] = idx * CAP;
    }
}

// ---- fused: blocks [0,nbb) bucket edges by target/256 into padded segments;
// blocks [nbb,..) run GEMM1 (MFMA): Hbf = bf16(X @ W1) ----
__global__ __launch_bounds__(256) void k_bg1(
    const int* __restrict__ row, const int* __restrict__ col, int e,
    int* __restrict__ gcur, int* __restrict__ pairs,
    const float* __restrict__ X, const unsigned short* __restrict__ W1t,
    unsigned* __restrict__ Hbf, int n, int nbb)
{
    extern __shared__ char dsm[];
    int tid = threadIdx.x;
    if (blockIdx.x < nbb) {
        // ---------------- bucket pass ----------------
        int* items = (int*)dsm;                                   // 24576 B
        unsigned short* bkt = (unsigned short*)(dsm + 24576);     // 12288 B
        int* hcnt  = (int*)(dsm + 24576 + 12288);                 //  2048 B
        int* lbase = hcnt + NBUCK_MAX;                            //  2048 B
        int e0 = blockIdx.x * EPB;
        int e1 = min(e, e0 + EPB);
        int m = e1 - e0;
        for (int b = tid; b < NBUCK_MAX; b += 256) hcnt[b] = 0;
        __syncthreads();
        for (int i = tid; i < m; i += 256) {
            int s = row[e0 + i];
            int d = col[e0 + i];
            items[i] = (s << BW_SH) | (d & (BW - 1));
            int b = d >> BW_SH;
            bkt[i] = (unsigned short)b;
            atomicAdd(&hcnt[b], 1);
        }
        __syncthreads();
        for (int b = tid; b < NBUCK_MAX; b += 256)
            lbase[b] = hcnt[b] ? atomicAdd(&gcur[b * GPAD], hcnt[b]) : 0;
        __syncthreads();
        for (int i = tid; i < m; i += 256) {
            int pos = atomicAdd(&lbase[bkt[i]], 1);
            pairs[pos] = items[i];
        }
    } else {
        // ---------------- GEMM1 (MFMA) ----------------
        unsigned short* ot = (unsigned short*)dsm;   // [4][16][136] = 17408 B
        int w = tid >> 6, L = tid & 63;
        int q = L >> 4, ml = L & 15;
        int nb0 = (blockIdx.x - nbb) * 64 + w * 16;
        int node = nb0 + ml;
        bool valid = node < n;
        const bf16x8* Bp = (const bf16x8*)W1t;
        f32x4 acc[8];
        #pragma unroll
        for (int cb = 0; cb < 8; ++cb) { acc[cb][0]=0.f; acc[cb][1]=0.f; acc[cb][2]=0.f; acc[cb][3]=0.f; }
        #pragma unroll
        for (int kc = 0; kc < 4; ++kc) {
            bf16x8 af = {0,0,0,0,0,0,0,0};
            if (valid) {
                const float4* xp = (const float4*)&X[(size_t)node * 128 + kc * 32 + q * 8];
                float4 xa = xp[0], xb = xp[1];
                af[0] = (short)bf16rne(xa.x); af[1] = (short)bf16rne(xa.y);
                af[2] = (short)bf16rne(xa.z); af[3] = (short)bf16rne(xa.w);
                af[4] = (short)bf16rne(xb.x); af[5] = (short)bf16rne(xb.y);
                af[6] = (short)bf16rne(xb.z); af[7] = (short)bf16rne(xb.w);
            }
            #pragma unroll
            for (int cb = 0; cb < 8; ++cb) {
                bf16x8 bfr = Bp[(cb * 16 + ml) * 16 + kc * 4 + q];
                acc[cb] = __builtin_amdgcn_mfma_f32_16x16x32_bf16(af, bfr, acc[cb], 0, 0, 0);
            }
        }
        #pragma unroll
        for (int cb = 0; cb < 8; ++cb)
            #pragma unroll
            for (int r = 0; r < 4; ++r)
                ot[(w * 16 + q * 4 + r) * 136 + cb * 16 + ml] =
                    (unsigned short)bf16rne(acc[cb][r]);
        __syncthreads();
        #pragma unroll
        for (int it = 0; it < 4; ++it) {
            int flat = it * 64 + L;
            int rw = flat >> 4, cg = flat & 15;
            int nd = nb0 + rw;
            if (nd < n) {
                uint4 v = *(const uint4*)&ot[(w * 16 + rw) * 136 + cg * 8];
                *(uint4*)&Hbf[(size_t)nd * 64 + cg * 4] = v;
            }
        }
    }
}

// ---- per-bucket hist + scan + LDS scatter; emits cnt/offs/dinv/esrc ----
__global__ __launch_bounds__(256) void k_fill5(
    const int* __restrict__ gcur, const int* __restrict__ pairs,
    int* __restrict__ offs, int* __restrict__ cnt, float* __restrict__ dinv,
    int* __restrict__ esrc, int n)
{
    __shared__ int lcnt[BW];
    __shared__ int loffs[BW];
    __shared__ int lcur[BW];
    __shared__ int sscan[256];
    __shared__ int lesrc[CAP];
    int b = blockIdx.x, tid = threadIdx.x;
    int t0 = b << BW_SH;
    int nt = min(n - t0, BW);
    int base = b * CAP;
    int m = min(gcur[b * GPAD] - base, CAP);
    lcnt[tid] = 0;
    __syncthreads();
    for (int i = tid; i < m; i += 256)
        atomicAdd(&lcnt[pairs[base + i] & (BW - 1)], 1);
    __syncthreads();
    int s = lcnt[tid];
    sscan[tid] = s; __syncthreads();
    for (int d = 1; d < 256; d <<= 1) {
        int u = (tid >= d) ? sscan[tid - d] : 0;
        __syncthreads();
        sscan[tid] += u;
        __syncthreads();
    }
    int ex = sscan[tid] - s;
    loffs[tid] = ex; lcur[tid] = ex;
    __syncthreads();
    if (tid < nt) {
        offs[t0 + tid] = base + ex;
        cnt[t0 + tid]  = s;
        dinv[t0 + tid] = 1.0f / sqrtf((float)(s + 1));
    }
    for (int i = tid; i < m; i += 256) {
        int it = pairs[base + i];
        int pos = atomicAdd(&lcur[it & (BW - 1)], 1);
        lesrc[pos] = it >> BW_SH;
    }
    __syncthreads();
    for (int i = tid; i < m; i += 256)
        esrc[base + i] = lesrc[i];
}

// ---- propagation over bf16 table: one wave per node, 2 edges in parallel,
// 16-edge unroll = 8 independent uint2 gathers in flight (at fabric roofline) ----
__global__ __launch_bounds__(256) void k_prop_bf(
    const unsigned* __restrict__ hbf, const float* __restrict__ dinv,
    const int* __restrict__ offs, const int* __restrict__ cnt,
    const int* __restrict__ esrc,
    unsigned* __restrict__ out_bf,
    const float* __restrict__ bias, int do_relu, int n)
{
    int wid  = (blockIdx.x * blockDim.x + threadIdx.x) >> 6;
    if (wid >= n) return;
    int lane = threadIdx.x & 63;
    int half = lane >> 5;
    int fl   = lane & 31;
    int v = wid;
    float dv = dinv[v];
    int start = offs[v];
    int deg   = cnt[v];
    const uint2* rows = (const uint2*)hbf;

    float a0 = 0.f, a1 = 0.f, a2 = 0.f, a3 = 0.f;
    if (half == 0) {
        uint2 r = rows[(size_t)v * 32 + fl];
        a0 = dv * bflo(r.x); a1 = dv * bfhi(r.x);
        a2 = dv * bflo(r.y); a3 = dv * bfhi(r.y);
    }
    for (int base = 0; base < deg; base += 64) {
        int m = min(64, deg - base);
        int s = 0; float w = 0.f;
        if (lane < m) { s = esrc[start + base + lane]; w = dinv[s]; }
        int j = 0;
        for (; j + 16 <= m; j += 16) {   // 8 row-loads in flight per wave
            int si[8]; float wi[8]; uint2 r[8];
            #pragma unroll
            for (int u = 0; u < 8; ++u) {
                si[u] = __shfl(s, j + 2 * u + half);
                wi[u] = __shfl(w, j + 2 * u + half);
            }
            #pragma unroll
            for (int u = 0; u < 8; ++u) r[u] = rows[(size_t)si[u] * 32 + fl];
            #pragma unroll
            for (int u = 0; u < 8; ++u) {
                a0 = fmaf(wi[u], bflo(r[u].x), a0);
                a1 = fmaf(wi[u], bfhi(r[u].x), a1);
                a2 = fmaf(wi[u], bflo(r[u].y), a2);
                a3 = fmaf(wi[u], bfhi(r[u].y), a3);
            }
        }
        for (; j + 8 <= m; j += 8) {
            int si[4]; float wi[4]; uint2 r[4];
            #pragma unroll
            for (int u = 0; u < 4; ++u) {
                si[u] = __shfl(s, j + 2 * u + half);
                wi[u] = __shfl(w, j + 2 * u + half);
            }
            #pragma unroll
            for (int u = 0; u < 4; ++u) r[u] = rows[(size_t)si[u] * 32 + fl];
            #pragma unroll
            for (int u = 0; u < 4; ++u) {
                a0 = fmaf(wi[u], bflo(r[u].x), a0);
                a1 = fmaf(wi[u], bfhi(r[u].x), a1);
                a2 = fmaf(wi[u], bflo(r[u].y), a2);
                a3 = fmaf(wi[u], bfhi(r[u].y), a3);
            }
        }
        for (; j < m; j += 2) {          // tail: lanes >= m carry w = 0
            int   ss = __shfl(s, j + half);
            float wv = __shfl(w, j + half);
            uint2 r = rows[(size_t)ss * 32 + fl];
            a0 = fmaf(wv, bflo(r.x), a0); a1 = fmaf(wv, bfhi(r.x), a1);
            a2 = fmaf(wv, bflo(r.y), a2); a3 = fmaf(wv, bfhi(r.y), a3);
        }
    }
    a0 += __shfl_xor(a0, 32);
    a1 += __shfl_xor(a1, 32);
    a2 += __shfl_xor(a2, 32);
    a3 += __shfl_xor(a3, 32);
    if (half == 0) {
        a0 *= dv; a1 *= dv; a2 *= dv; a3 *= dv;
        if (bias) {
            a0 += bias[fl * 4 + 0]; a1 += bias[fl * 4 + 1];
            a2 += bias[fl * 4 + 2]; a3 += bias[fl * 4 + 3];
        }
        if (do_relu) {
            a0 = fmaxf(a0, 0.f); a1 = fmaxf(a1, 0.f);
            a2 = fmaxf(a2, 0.f); a3 = fmaxf(a3, 0.f);
        }
        uint2 pk;
        pk.x = (bf16rne(a1) << 16) | bf16rne(a0);
        pk.y = (bf16rne(a3) << 16) | bf16rne(a2);
        ((uint2*)out_bf)[(size_t)v * 32 + fl] = pk;
    }
}

// ---- GEMM2 (MFMA): out = G @ [Wmu|Wls] + [bmu|bls], split fp32 write ----
__global__ __launch_bounds__(256) void k_gemm2(
    const unsigned* __restrict__ Gbf, const unsigned short* __restrict__ Wct,
    const float* __restrict__ bcat, float* __restrict__ out, int n)
{
    __shared__ float ot[4][16][132];
    int tid = threadIdx.x;
    int w = tid >> 6, L = tid & 63;
    int q = L >> 4, ml = L & 15;
    int nb0 = blockIdx.x * 64 + w * 16;
    int node = nb0 + ml;
    bool valid = node < n;
    const bf16x8* Ap = (const bf16x8*)Gbf;
    const bf16x8* Bp = (const bf16x8*)Wct;
    f32x4 acc[8];
    #pragma unroll
    for (int cb = 0; cb < 8; ++cb) { acc[cb][0]=0.f; acc[cb][1]=0.f; acc[cb][2]=0.f; acc[cb][3]=0.f; }
    #pragma unroll
    for (int kc = 0; kc < 4; ++kc) {
        bf16x8 af = {0,0,0,0,0,0,0,0};
        if (valid) af = Ap[(size_t)node * 16 + kc * 4 + q];
        #pragma unroll
        for (int cb = 0; cb < 8; ++cb) {
            bf16x8 bfr = Bp[(cb * 16 + ml) * 16 + kc * 4 + q];
            acc[cb] = __builtin_amdgcn_mfma_f32_16x16x32_bf16(af, bfr, acc[cb], 0, 0, 0);
        }
    }
    #pragma unroll
    for (int cb = 0; cb < 8; ++cb)
        #pragma unroll
        for (int r = 0; r < 4; ++r)
            ot[w][q * 4 + r][cb * 16 + ml] = acc[cb][r];
    __syncthreads();
    #pragma unroll
    for (int it = 0; it < 8; ++it) {
        int flat = it * 64 + L;
        int row = flat >> 5, c4 = flat & 31;
        int col = c4 * 4;
        int nd = nb0 + row;
        if (nd < n) {
            float4 v = *(const float4*)&ot[w][row][col];
            float4 bb = *(const float4*)&bcat[col];
            v.x += bb.x; v.y += bb.y; v.z += bb.z; v.w += bb.w;
            size_t off = (col < 64)
                ? ((size_t)nd * 64 + col)
                : ((size_t)n * 64 + (size_t)nd * 64 + (col - 64));
            *(float4*)&out[off] = v;
        }
    }
}

extern "C" void kernel_launch(void* const* d_in, const int* in_sizes, int n_in,
                              void* d_out, int out_size, void* d_ws, size_t ws_size,
                              hipStream_t stream) {
    const float* x   = (const float*)d_in[0];
    const int*   ei  = (const int*)d_in[1];
    const float* W1  = (const float*)d_in[3];
    const float* b1  = (const float*)d_in[4];
    const float* Wmu = (const float*)d_in[5];
    const float* bmu = (const float*)d_in[6];
    const float* Wls = (const float*)d_in[7];
    const float* bls = (const float*)d_in[8];
    float* out = (float*)d_out;

    int n = in_sizes[0] / 128;   // 100000
    int e = in_sizes[1] / 2;     // 1600000
    const int* erow = ei;        // sources
    const int* ecol = ei + e;    // targets
    int nbuck = (n + BW - 1) >> BW_SH;        // 391
    int nbb   = (e + EPB - 1) / EPB;          // 261

    char* p = (char*)d_ws;
    auto alloc = [&](size_t bytes) -> char* {
        char* q = p; p += (bytes + 255) & ~(size_t)255; return q;
    };
    int*            gcur  = (int*)           alloc((size_t)NBUCK_MAX * GPAD * 4);
    int*            cnt   = (int*)           alloc((size_t)n * 4);
    int*            offs  = (int*)           alloc((size_t)n * 4);
    float*          dinv  = (float*)         alloc((size_t)n * 4);
    int*            esrc  = (int*)           alloc((size_t)nbuck * CAP * 4);
    unsigned short* W1t   = (unsigned short*)alloc(128 * 128 * 2);
    unsigned short* Wct   = (unsigned short*)alloc(128 * 128 * 2);
    float*          bcat  = (float*)         alloc(128 * 4);
    unsigned*       hbf   = (unsigned*)      alloc((size_t)n * 64 * 4);
    unsigned*       h1bf  = (unsigned*)      alloc((size_t)n * 64 * 4);
    unsigned*       gbf   = (unsigned*)      alloc((size_t)n * 64 * 4);
    int*            pairs = (int*)gbf;   // dead before prop2 writes gbf

    k_wprep<<<260, 128, 0, stream>>>(W1, Wmu, Wls, bmu, bls, W1t, Wct, bcat,
                                     gcur, nbuck);
    k_bg1<<<nbb + (n + 63) / 64, 256, 40960, stream>>>(
        erow, ecol, e, gcur, pairs, x, W1t, hbf, n, nbb);
    k_fill5<<<nbuck, 256, 0, stream>>>(gcur, pairs, offs, cnt, dinv, esrc, n);

    k_prop_bf<<<(n + 3) / 4, 256, 0, stream>>>(hbf, dinv, offs, cnt, esrc,
                                               h1bf, b1, 1, n);
    k_prop_bf<<<(n + 3) / 4, 256, 0, stream>>>(h1bf, dinv, offs, cnt, esrc,
                                               gbf, nullptr, 0, n);
    k_gemm2<<<(n + 63) / 64, 256, 0, stream>>>(gbf, Wct, bcat, out, n);
}